// Round 2
// baseline (562.685 us; speedup 1.0000x reference)
//
#include <hip/hip_runtime.h>

#define HID 128
#define CLS 10

// ---------------- CSR build ----------------

__global__ __launch_bounds__(256) void zero_init(int* degi, int* fillc,
                                                 float* pooled, int* cnt,
                                                 int n, int gh, int g) {
  int i = blockIdx.x * 256 + threadIdx.x;
  if (i < n) { degi[i] = 0; fillc[i] = 0; }
  if (i < gh) pooled[i] = 0.f;
  if (i < g) cnt[i] = 0;
}

__global__ __launch_bounds__(256) void degree_k(const int* __restrict__ dst,
                                                int* __restrict__ degi, int E) {
  int e = blockIdx.x * 256 + threadIdx.x;
  if (e < E) atomicAdd(&degi[dst[e]], 1);
}

__global__ __launch_bounds__(256) void count_k(const int* __restrict__ batch,
                                               int* __restrict__ cnt, int n) {
  int i = blockIdx.x * 256 + threadIdx.x;
  if (i < n) atomicAdd(&cnt[batch[i]], 1);
}

__global__ __launch_bounds__(256) void dinv_k(const int* __restrict__ degi,
                                              float* __restrict__ dinv, int n) {
  int i = blockIdx.x * 256 + threadIdx.x;
  if (i < n) dinv[i] = rsqrtf((float)degi[i] + 1.0f);  // +1 for self-loop
}

__global__ __launch_bounds__(256) void scan_chunk(const int* __restrict__ degi,
                                                  int* __restrict__ row_ptr,
                                                  int* __restrict__ blockSums, int n) {
  __shared__ int sd[256];
  int t = threadIdx.x;
  int i = blockIdx.x * 256 + t;
  int v = (i < n) ? degi[i] : 0;
  sd[t] = v;
  for (int off = 1; off < 256; off <<= 1) {
    __syncthreads();
    int x = (t >= off) ? sd[t - off] : 0;
    __syncthreads();
    sd[t] += x;
  }
  if (i < n) row_ptr[i] = sd[t] - v;  // exclusive within chunk
  if (t == 255) blockSums[blockIdx.x] = sd[255];
}

__global__ __launch_bounds__(256) void scan_top(int* blockSums, int nb) {
  __shared__ int sd[256];
  int t = threadIdx.x;
  int v = (t < nb) ? blockSums[t] : 0;
  sd[t] = v;
  for (int off = 1; off < 256; off <<= 1) {
    __syncthreads();
    int x = (t >= off) ? sd[t - off] : 0;
    __syncthreads();
    sd[t] += x;
  }
  if (t < nb) blockSums[t] = sd[t] - v;  // exclusive block offsets
}

__global__ __launch_bounds__(256) void scan_add(int* __restrict__ row_ptr,
                                                const int* __restrict__ blockSums,
                                                int n, int E) {
  int i = blockIdx.x * 256 + threadIdx.x;
  if (i < n) row_ptr[i] += blockSums[blockIdx.x];
  if (i == 0) row_ptr[n] = E;
}

__global__ __launch_bounds__(256) void csr_fill(const int* __restrict__ src,
                                                const int* __restrict__ dst,
                                                const float* __restrict__ dinv,
                                                const int* __restrict__ row_ptr,
                                                int* __restrict__ fillc,
                                                int* __restrict__ col_src,
                                                float* __restrict__ edge_w, int E) {
  int e = blockIdx.x * 256 + threadIdx.x;
  if (e >= E) return;
  int s = src[e], d = dst[e];
  int slot = atomicAdd(&fillc[d], 1);
  int idx = row_ptr[d] + slot;
  col_src[idx] = s;
  edge_w[idx] = dinv[s] * dinv[d];
}

// ---------------- fp32 GEMM: T[n,128] = A[n,128] @ W[128,128] ----------------

__global__ __launch_bounds__(256) void gemm128(const float* __restrict__ A,
                                               const float* __restrict__ W,
                                               float* __restrict__ T, int nrows) {
  __shared__ float sA[64 * 128];  // 32 KB
  __shared__ float sW[128 * 64];  // 32 KB
  int tid = threadIdx.x;
  int row0 = blockIdx.x * 64;
  int col0 = blockIdx.y * 64;

  for (int i = tid * 4; i < 128 * 64; i += 1024) {
    int k = i >> 6, cc = i & 63;
    *(float4*)&sW[i] = *(const float4*)&W[k * 128 + col0 + cc];
  }
  for (int i = tid * 4; i < 64 * 128; i += 1024) {
    int r = i >> 7;
    int gr = row0 + r;
    float4 v = make_float4(0.f, 0.f, 0.f, 0.f);
    if (gr < nrows) v = *(const float4*)&A[gr * 128 + (i & 127)];
    *(float4*)&sA[i] = v;
  }
  __syncthreads();

  int ry = (tid >> 5) * 8;   // 8 row-groups of 8
  int cx = (tid & 31) * 2;   // 32 col-groups of 2
  float2 acc[8];
#pragma unroll
  for (int r = 0; r < 8; ++r) acc[r] = make_float2(0.f, 0.f);

  for (int k0 = 0; k0 < 128; k0 += 4) {
    float4 a[8];
#pragma unroll
    for (int r = 0; r < 8; ++r) a[r] = *(float4*)&sA[(ry + r) * 128 + k0];
#pragma unroll
    for (int kk = 0; kk < 4; ++kk) {
      float2 w = *(float2*)&sW[(k0 + kk) * 64 + cx];
#pragma unroll
      for (int r = 0; r < 8; ++r) {
        float av = (kk == 0) ? a[r].x : (kk == 1) ? a[r].y : (kk == 2) ? a[r].z : a[r].w;
        acc[r].x += av * w.x;
        acc[r].y += av * w.y;
      }
    }
  }
#pragma unroll
  for (int r = 0; r < 8; ++r) {
    int gr = row0 + ry + r;
    if (gr < nrows) *(float2*)&T[gr * 128 + col0 + cx] = acc[r];
  }
}

// ---------------- aggregate ----------------

__global__ __launch_bounds__(256) void aggregate(const float* __restrict__ T,
                                                 const float* __restrict__ dinv,
                                                 const int* __restrict__ row_ptr,
                                                 const int* __restrict__ col_src,
                                                 const float* __restrict__ edge_w,
                                                 const float* __restrict__ bias,
                                                 float* __restrict__ Hout, int n) {
  int node = (blockIdx.x * 256 + threadIdx.x) >> 6;
  if (node >= n) return;
  int lane = threadIdx.x & 63;
  int c = lane * 2;
  float di = dinv[node];
  float2 t0 = *(const float2*)&T[node * HID + c];
  float ax = di * di * t0.x;
  float ay = di * di * t0.y;
  int j = row_ptr[node], end = row_ptr[node + 1];
  for (; j + 4 <= end; j += 4) {
    int s0 = col_src[j], s1 = col_src[j + 1], s2 = col_src[j + 2], s3 = col_src[j + 3];
    float w0 = edge_w[j], w1 = edge_w[j + 1], w2 = edge_w[j + 2], w3 = edge_w[j + 3];
    float2 v0 = *(const float2*)&T[s0 * HID + c];
    float2 v1 = *(const float2*)&T[s1 * HID + c];
    float2 v2 = *(const float2*)&T[s2 * HID + c];
    float2 v3 = *(const float2*)&T[s3 * HID + c];
    ax += w0 * v0.x + w1 * v1.x + w2 * v2.x + w3 * v3.x;
    ay += w0 * v0.y + w1 * v1.y + w2 * v2.y + w3 * v3.y;
  }
  for (; j < end; ++j) {
    int s = col_src[j];
    float w = edge_w[j];
    float2 v = *(const float2*)&T[s * HID + c];
    ax += w * v.x;
    ay += w * v.y;
  }
  ax = fmaxf(ax + bias[c], 0.f);
  ay = fmaxf(ay + bias[c + 1], 0.f);
  *(float2*)&Hout[node * HID + c] = make_float2(ax, ay);
}

// ---------------- pooling: parallel segmented partial sums ----------------
// One block per 64-node chunk; batch is sorted so each chunk spans ~1-2 graphs.
// Thread t owns column t; flush a run's accumulator with one atomicAdd.

__global__ __launch_bounds__(128) void pool_partial(const float* __restrict__ Hin,
                                                    const int* __restrict__ batch,
                                                    float* __restrict__ pooled, int n) {
  int t = threadIdx.x;
  int s = blockIdx.x * 64;
  if (s >= n) return;
  int e = min(s + 64, n);
  int g = batch[s];
  float acc = 0.f;
  for (int i = s; i < e; ++i) {
    int bi = batch[i];  // wave-uniform broadcast load
    if (bi != g) {
      atomicAdd(&pooled[g * HID + t], acc);
      acc = 0.f;
      g = bi;
    }
    acc += Hin[i * HID + t];
  }
  atomicAdd(&pooled[g * HID + t], acc);
}

__global__ __launch_bounds__(128) void classify_k(const float* __restrict__ pooled,
                                                  const int* __restrict__ cnt,
                                                  const float* __restrict__ Wl,
                                                  const float* __restrict__ bl,
                                                  float* __restrict__ out) {
  int g = blockIdx.x;
  int t = threadIdx.x;
  __shared__ float p[HID];
  float c = fmaxf((float)cnt[g], 1.0f);
  p[t] = pooled[g * HID + t] / c;
  __syncthreads();
  if (t < CLS) {
    float o = bl[t];
    for (int j = 0; j < HID; ++j) o += p[j] * Wl[j * CLS + t];
    out[g * CLS + t] = o;
  }
}

// ---------------- launch ----------------

extern "C" void kernel_launch(void* const* d_in, const int* in_sizes, int n_in,
                              void* d_out, int out_size, void* d_ws, size_t ws_size,
                              hipStream_t stream) {
  const float* x  = (const float*)d_in[0];
  const float* W1 = (const float*)d_in[1];
  const float* b1 = (const float*)d_in[2];
  const float* W2 = (const float*)d_in[3];
  const float* b2 = (const float*)d_in[4];
  const float* W3 = (const float*)d_in[5];
  const float* b3 = (const float*)d_in[6];
  const float* Wl = (const float*)d_in[7];
  const float* bl = (const float*)d_in[8];
  const int* edge_index = (const int*)d_in[9];
  const int* batch = (const int*)d_in[10];

  const int N = in_sizes[10];
  const int E = in_sizes[9] / 2;
  const int G = out_size / CLS;
  const int* src = edge_index;
  const int* dst = edge_index + E;

  // workspace carve (256B aligned)
  uintptr_t p = (uintptr_t)d_ws;
  auto take = [&](size_t bytes) -> void* {
    void* r = (void*)p;
    p += (bytes + 255) & ~(size_t)255;
    return r;
  };
  int*   degi      = (int*)take((size_t)N * 4);
  int*   fillc     = (int*)take((size_t)N * 4);
  int*   row_ptr   = (int*)take((size_t)(N + 1) * 4);
  int*   blockSums = (int*)take(256 * 4);
  float* dinv      = (float*)take((size_t)N * 4);
  int*   col_src   = (int*)take((size_t)E * 4);
  float* edge_w    = (float*)take((size_t)E * 4);
  float* bufT      = (float*)take((size_t)N * HID * 4);
  float* bufH      = (float*)take((size_t)N * HID * 4);
  float* pooled    = (float*)take((size_t)G * HID * 4);
  int*   cnt       = (int*)take((size_t)G * 4);

  int nbN = (N + 255) / 256;
  int nbE = (E + 255) / 256;

  zero_init<<<nbN, 256, 0, stream>>>(degi, fillc, pooled, cnt, N, G * HID, G);
  degree_k<<<nbE, 256, 0, stream>>>(dst, degi, E);
  count_k<<<nbN, 256, 0, stream>>>(batch, cnt, N);
  dinv_k<<<nbN, 256, 0, stream>>>(degi, dinv, N);
  scan_chunk<<<nbN, 256, 0, stream>>>(degi, row_ptr, blockSums, N);
  scan_top<<<1, 256, 0, stream>>>(blockSums, nbN);
  scan_add<<<nbN, 256, 0, stream>>>(row_ptr, blockSums, N, E);
  csr_fill<<<nbE, 256, 0, stream>>>(src, dst, dinv, row_ptr, fillc, col_src, edge_w, E);

  dim3 ggrid((N + 63) / 64, 2);
  int aggBlocks = (N * 64 + 255) / 256;

  // layer 1
  gemm128<<<ggrid, 256, 0, stream>>>(x, W1, bufT, N);
  aggregate<<<aggBlocks, 256, 0, stream>>>(bufT, dinv, row_ptr, col_src, edge_w, b1, bufH, N);
  // layer 2
  gemm128<<<ggrid, 256, 0, stream>>>(bufH, W2, bufT, N);
  aggregate<<<aggBlocks, 256, 0, stream>>>(bufT, dinv, row_ptr, col_src, edge_w, b2, bufH, N);
  // layer 3
  gemm128<<<ggrid, 256, 0, stream>>>(bufH, W3, bufT, N);
  aggregate<<<aggBlocks, 256, 0, stream>>>(bufT, dinv, row_ptr, col_src, edge_w, b3, bufH, N);

  pool_partial<<<(N + 63) / 64, 128, 0, stream>>>(bufH, batch, pooled, N);
  classify_k<<<G, 128, 0, stream>>>(pooled, cnt, Wl, bl, (float*)d_out);
}

// Round 3
// 452.467 us; speedup vs baseline: 1.2436x; 1.2436x over previous
//
#include <hip/hip_runtime.h>

#define HID 128
#define CLS 10

// ---------------- CSR build ----------------

__global__ __launch_bounds__(256) void zero_init(int* degi, int* fillc,
                                                 float* pooled, int n, int gh) {
  int i = blockIdx.x * 256 + threadIdx.x;
  if (i < n) { degi[i] = 0; fillc[i] = 0; }
  if (i < gh) pooled[i] = 0.f;
}

__global__ __launch_bounds__(256) void degree_k(const int* __restrict__ dst,
                                                int* __restrict__ degi, int E) {
  int e = blockIdx.x * 256 + threadIdx.x;
  if (e < E) atomicAdd(&degi[dst[e]], 1);
}

__global__ __launch_bounds__(256) void dinv_k(const int* __restrict__ degi,
                                              float* __restrict__ dinv, int n) {
  int i = blockIdx.x * 256 + threadIdx.x;
  if (i < n) dinv[i] = rsqrtf((float)degi[i] + 1.0f);  // +1 for self-loop
}

__global__ __launch_bounds__(256) void scan_chunk(const int* __restrict__ degi,
                                                  int* __restrict__ row_ptr,
                                                  int* __restrict__ blockSums, int n) {
  __shared__ int sd[256];
  int t = threadIdx.x;
  int i = blockIdx.x * 256 + t;
  int v = (i < n) ? degi[i] : 0;
  sd[t] = v;
  for (int off = 1; off < 256; off <<= 1) {
    __syncthreads();
    int x = (t >= off) ? sd[t - off] : 0;
    __syncthreads();
    sd[t] += x;
  }
  if (i < n) row_ptr[i] = sd[t] - v;  // exclusive within chunk
  if (t == 255) blockSums[blockIdx.x] = sd[255];
}

__global__ __launch_bounds__(256) void scan_top(int* blockSums, int nb) {
  __shared__ int sd[256];
  int t = threadIdx.x;
  int v = (t < nb) ? blockSums[t] : 0;
  sd[t] = v;
  for (int off = 1; off < 256; off <<= 1) {
    __syncthreads();
    int x = (t >= off) ? sd[t - off] : 0;
    __syncthreads();
    sd[t] += x;
  }
  if (t < nb) blockSums[t] = sd[t] - v;  // exclusive block offsets
}

__global__ __launch_bounds__(256) void scan_add(int* __restrict__ row_ptr,
                                                const int* __restrict__ blockSums,
                                                int n, int E) {
  int i = blockIdx.x * 256 + threadIdx.x;
  if (i < n) row_ptr[i] += blockSums[blockIdx.x];
  if (i == 0) row_ptr[n] = E;
}

__global__ __launch_bounds__(256) void csr_fill(const int* __restrict__ src,
                                                const int* __restrict__ dst,
                                                const float* __restrict__ dinv,
                                                const int* __restrict__ row_ptr,
                                                int* __restrict__ fillc,
                                                int* __restrict__ col_src,
                                                float* __restrict__ edge_w, int E) {
  int e = blockIdx.x * 256 + threadIdx.x;
  if (e >= E) return;
  int s = src[e], d = dst[e];
  int slot = atomicAdd(&fillc[d], 1);
  int idx = row_ptr[d] + slot;
  col_src[idx] = s;
  edge_w[idx] = dinv[s] * dinv[d];
}

// ---------------- fp32 GEMM: T[n,128] = A[n,128] @ W[128,128] ----------------

__global__ __launch_bounds__(256) void gemm128(const float* __restrict__ A,
                                               const float* __restrict__ W,
                                               float* __restrict__ T, int nrows) {
  __shared__ float sA[64 * 128];  // 32 KB
  __shared__ float sW[128 * 64];  // 32 KB
  int tid = threadIdx.x;
  int row0 = blockIdx.x * 64;
  int col0 = blockIdx.y * 64;

  for (int i = tid * 4; i < 128 * 64; i += 1024) {
    int k = i >> 6, cc = i & 63;
    *(float4*)&sW[i] = *(const float4*)&W[k * 128 + col0 + cc];
  }
  for (int i = tid * 4; i < 64 * 128; i += 1024) {
    int r = i >> 7;
    int gr = row0 + r;
    float4 v = make_float4(0.f, 0.f, 0.f, 0.f);
    if (gr < nrows) v = *(const float4*)&A[gr * 128 + (i & 127)];
    *(float4*)&sA[i] = v;
  }
  __syncthreads();

  int ry = (tid >> 5) * 8;   // 8 row-groups of 8
  int cx = (tid & 31) * 2;   // 32 col-groups of 2
  float2 acc[8];
#pragma unroll
  for (int r = 0; r < 8; ++r) acc[r] = make_float2(0.f, 0.f);

  for (int k0 = 0; k0 < 128; k0 += 4) {
    float4 a[8];
#pragma unroll
    for (int r = 0; r < 8; ++r) a[r] = *(float4*)&sA[(ry + r) * 128 + k0];
#pragma unroll
    for (int kk = 0; kk < 4; ++kk) {
      float2 w = *(float2*)&sW[(k0 + kk) * 64 + cx];
#pragma unroll
      for (int r = 0; r < 8; ++r) {
        float av = (kk == 0) ? a[r].x : (kk == 1) ? a[r].y : (kk == 2) ? a[r].z : a[r].w;
        acc[r].x += av * w.x;
        acc[r].y += av * w.y;
      }
    }
  }
#pragma unroll
  for (int r = 0; r < 8; ++r) {
    int gr = row0 + ry + r;
    if (gr < nrows) *(float2*)&T[gr * 128 + col0 + cx] = acc[r];
  }
}

// ---------------- aggregate ----------------

__global__ __launch_bounds__(256) void aggregate(const float* __restrict__ T,
                                                 const float* __restrict__ dinv,
                                                 const int* __restrict__ row_ptr,
                                                 const int* __restrict__ col_src,
                                                 const float* __restrict__ edge_w,
                                                 const float* __restrict__ bias,
                                                 float* __restrict__ Hout, int n) {
  int node = (blockIdx.x * 256 + threadIdx.x) >> 6;
  if (node >= n) return;
  int lane = threadIdx.x & 63;
  int c = lane * 2;
  float di = dinv[node];
  float2 t0 = *(const float2*)&T[node * HID + c];
  float ax = di * di * t0.x;
  float ay = di * di * t0.y;
  int j = row_ptr[node], end = row_ptr[node + 1];
  for (; j + 4 <= end; j += 4) {
    int s0 = col_src[j], s1 = col_src[j + 1], s2 = col_src[j + 2], s3 = col_src[j + 3];
    float w0 = edge_w[j], w1 = edge_w[j + 1], w2 = edge_w[j + 2], w3 = edge_w[j + 3];
    float2 v0 = *(const float2*)&T[s0 * HID + c];
    float2 v1 = *(const float2*)&T[s1 * HID + c];
    float2 v2 = *(const float2*)&T[s2 * HID + c];
    float2 v3 = *(const float2*)&T[s3 * HID + c];
    ax += w0 * v0.x + w1 * v1.x + w2 * v2.x + w3 * v3.x;
    ay += w0 * v0.y + w1 * v1.y + w2 * v2.y + w3 * v3.y;
  }
  for (; j < end; ++j) {
    int s = col_src[j];
    float w = edge_w[j];
    float2 v = *(const float2*)&T[s * HID + c];
    ax += w * v.x;
    ay += w * v.y;
  }
  ax = fmaxf(ax + bias[c], 0.f);
  ay = fmaxf(ay + bias[c + 1], 0.f);
  *(float2*)&Hout[node * HID + c] = make_float2(ax, ay);
}

// ---------------- pooling: parallel segmented partial sums ----------------

__global__ __launch_bounds__(128) void pool_partial(const float* __restrict__ Hin,
                                                    const int* __restrict__ batch,
                                                    float* __restrict__ pooled, int n) {
  int t = threadIdx.x;
  int s = blockIdx.x * 64;
  if (s >= n) return;
  int e = min(s + 64, n);
  int g = batch[s];
  float acc = 0.f;
  for (int i = s; i < e; ++i) {
    int bi = batch[i];  // wave-uniform broadcast load
    if (bi != g) {
      atomicAdd(&pooled[g * HID + t], acc);
      acc = 0.f;
      g = bi;
    }
    acc += Hin[i * HID + t];
  }
  atomicAdd(&pooled[g * HID + t], acc);
}

// classify + per-graph count via binary search on sorted batch (no atomics)

__global__ __launch_bounds__(128) void classify_k(const float* __restrict__ pooled,
                                                  const int* __restrict__ batch,
                                                  const float* __restrict__ Wl,
                                                  const float* __restrict__ bl,
                                                  float* __restrict__ out, int n) {
  int g = blockIdx.x;
  int t = threadIdx.x;
  // wave-uniform binary searches: count = lb(g+1) - lb(g)
  int lo = 0, hi = n;
  while (lo < hi) { int mid = (lo + hi) >> 1; if (batch[mid] < g) lo = mid + 1; else hi = mid; }
  int s = lo;
  hi = n;
  while (lo < hi) { int mid = (lo + hi) >> 1; if (batch[mid] < g + 1) lo = mid + 1; else hi = mid; }
  float c = fmaxf((float)(lo - s), 1.0f);
  __shared__ float p[HID];
  p[t] = pooled[g * HID + t] / c;
  __syncthreads();
  if (t < CLS) {
    float o = bl[t];
    for (int j = 0; j < HID; ++j) o += p[j] * Wl[j * CLS + t];
    out[g * CLS + t] = o;
  }
}

// ---------------- launch ----------------

extern "C" void kernel_launch(void* const* d_in, const int* in_sizes, int n_in,
                              void* d_out, int out_size, void* d_ws, size_t ws_size,
                              hipStream_t stream) {
  const float* x  = (const float*)d_in[0];
  const float* W1 = (const float*)d_in[1];
  const float* b1 = (const float*)d_in[2];
  const float* W2 = (const float*)d_in[3];
  const float* b2 = (const float*)d_in[4];
  const float* W3 = (const float*)d_in[5];
  const float* b3 = (const float*)d_in[6];
  const float* Wl = (const float*)d_in[7];
  const float* bl = (const float*)d_in[8];
  const int* edge_index = (const int*)d_in[9];
  const int* batch = (const int*)d_in[10];

  const int N = in_sizes[10];
  const int E = in_sizes[9] / 2;
  const int G = out_size / CLS;
  const int* src = edge_index;
  const int* dst = edge_index + E;

  // workspace carve (256B aligned)
  uintptr_t p = (uintptr_t)d_ws;
  auto take = [&](size_t bytes) -> void* {
    void* r = (void*)p;
    p += (bytes + 255) & ~(size_t)255;
    return r;
  };
  int*   degi      = (int*)take((size_t)N * 4);
  int*   fillc     = (int*)take((size_t)N * 4);
  int*   row_ptr   = (int*)take((size_t)(N + 1) * 4);
  int*   blockSums = (int*)take(256 * 4);
  float* dinv      = (float*)take((size_t)N * 4);
  int*   col_src   = (int*)take((size_t)E * 4);
  float* edge_w    = (float*)take((size_t)E * 4);
  float* bufT      = (float*)take((size_t)N * HID * 4);
  float* bufH      = (float*)take((size_t)N * HID * 4);
  float* pooled    = (float*)take((size_t)G * HID * 4);

  int nbN = (N + 255) / 256;
  int nbE = (E + 255) / 256;

  zero_init<<<nbN, 256, 0, stream>>>(degi, fillc, pooled, N, G * HID);
  degree_k<<<nbE, 256, 0, stream>>>(dst, degi, E);
  dinv_k<<<nbN, 256, 0, stream>>>(degi, dinv, N);
  scan_chunk<<<nbN, 256, 0, stream>>>(degi, row_ptr, blockSums, N);
  scan_top<<<1, 256, 0, stream>>>(blockSums, nbN);
  scan_add<<<nbN, 256, 0, stream>>>(row_ptr, blockSums, N, E);
  csr_fill<<<nbE, 256, 0, stream>>>(src, dst, dinv, row_ptr, fillc, col_src, edge_w, E);

  dim3 ggrid((N + 63) / 64, 2);
  int aggBlocks = (N * 64 + 255) / 256;

  // layer 1
  gemm128<<<ggrid, 256, 0, stream>>>(x, W1, bufT, N);
  aggregate<<<aggBlocks, 256, 0, stream>>>(bufT, dinv, row_ptr, col_src, edge_w, b1, bufH, N);
  // layer 2
  gemm128<<<ggrid, 256, 0, stream>>>(bufH, W2, bufT, N);
  aggregate<<<aggBlocks, 256, 0, stream>>>(bufT, dinv, row_ptr, col_src, edge_w, b2, bufH, N);
  // layer 3
  gemm128<<<ggrid, 256, 0, stream>>>(bufH, W3, bufT, N);
  aggregate<<<aggBlocks, 256, 0, stream>>>(bufT, dinv, row_ptr, col_src, edge_w, b3, bufH, N);

  pool_partial<<<(N + 63) / 64, 128, 0, stream>>>(bufH, batch, pooled, N);
  classify_k<<<G, 128, 0, stream>>>(pooled, batch, Wl, bl, (float*)d_out, N);
}

// Round 4
// 414.363 us; speedup vs baseline: 1.3580x; 1.0920x over previous
//
#include <hip/hip_runtime.h>

#define HID 128
#define CLS 10

// ---------------- CSR build ----------------

__global__ __launch_bounds__(256) void zero_init(int* degi, int* fillc,
                                                 float* pooled, int n, int gh) {
  int i = blockIdx.x * 256 + threadIdx.x;
  if (i < n) { degi[i] = 0; fillc[i] = 0; }
  if (i < gh) pooled[i] = 0.f;
}

__global__ __launch_bounds__(256) void degree_k(const int* __restrict__ dst,
                                                int* __restrict__ degi, int E) {
  int e = blockIdx.x * 256 + threadIdx.x;
  if (e < E) atomicAdd(&degi[dst[e]], 1);
}

__global__ __launch_bounds__(256) void dinv_k(const int* __restrict__ degi,
                                              float* __restrict__ dinv, int n) {
  int i = blockIdx.x * 256 + threadIdx.x;
  if (i < n) dinv[i] = rsqrtf((float)degi[i] + 1.0f);  // +1 for self-loop
}

__global__ __launch_bounds__(256) void scan_chunk(const int* __restrict__ degi,
                                                  int* __restrict__ row_ptr,
                                                  int* __restrict__ blockSums, int n) {
  __shared__ int sd[256];
  int t = threadIdx.x;
  int i = blockIdx.x * 256 + t;
  int v = (i < n) ? degi[i] : 0;
  sd[t] = v;
  for (int off = 1; off < 256; off <<= 1) {
    __syncthreads();
    int x = (t >= off) ? sd[t - off] : 0;
    __syncthreads();
    sd[t] += x;
  }
  if (i < n) row_ptr[i] = sd[t] - v;
  if (t == 255) blockSums[blockIdx.x] = sd[255];
}

__global__ __launch_bounds__(256) void scan_top(int* blockSums, int nb) {
  __shared__ int sd[256];
  int t = threadIdx.x;
  int v = (t < nb) ? blockSums[t] : 0;
  sd[t] = v;
  for (int off = 1; off < 256; off <<= 1) {
    __syncthreads();
    int x = (t >= off) ? sd[t - off] : 0;
    __syncthreads();
    sd[t] += x;
  }
  if (t < nb) blockSums[t] = sd[t] - v;
}

__global__ __launch_bounds__(256) void scan_add(int* __restrict__ row_ptr,
                                                const int* __restrict__ blockSums,
                                                int n, int E) {
  int i = blockIdx.x * 256 + threadIdx.x;
  if (i < n) row_ptr[i] += blockSums[blockIdx.x];
  if (i == 0) row_ptr[n] = E;
}

// only col_src is written now (normalization folded into GEMM epilogue)
__global__ __launch_bounds__(256) void csr_fill(const int* __restrict__ src,
                                                const int* __restrict__ dst,
                                                const int* __restrict__ row_ptr,
                                                int* __restrict__ fillc,
                                                int* __restrict__ col_src, int E) {
  int e = blockIdx.x * 256 + threadIdx.x;
  if (e >= E) return;
  int s = src[e], d = dst[e];
  int slot = atomicAdd(&fillc[d], 1);
  col_src[row_ptr[d] + slot] = s;
}

// ---------------- fp32 GEMM: T[r,:] = dinv[r] * (A[r,:] @ W) ----------------
// M64 x N128 x K8, double-buffered LDS (12.5 KB), thread tile 4x8.
// sA transposed [k][m] (pad 68 keeps 16B alignment + spreads banks).

#define TM 64
#define TK 8

__global__ __launch_bounds__(256) void gemm_scaled(const float* __restrict__ A,
                                                   const float* __restrict__ W,
                                                   const float* __restrict__ dinv,
                                                   float* __restrict__ T, int nrows) {
  __shared__ float sA[2][TK][68];    // 4.25 KB
  __shared__ float sB[2][TK][HID];   // 8 KB
  int tid = threadIdx.x;
  int row0 = blockIdx.x * TM;

  // staging coords
  int am = tid >> 2;            // 0..63 : tile row
  int ak = (tid & 3) * 2;       // 0,2,4,6 : k pair within kblock
  int bk = tid >> 5;            // 0..7
  int bn = (tid & 31) * 4;      // 0..124
  int agr = row0 + am;
  bool aok = (agr < nrows);

  // compute coords: 16x16 threads, each 4 rows x 8 cols
  int m0 = (tid & 15) * 4;
  int n0 = (tid >> 4) * 8;

  float2 ra;
  float4 rb;

  // prologue: kb = 0
  ra = aok ? *(const float2*)&A[(size_t)agr * HID + ak] : make_float2(0.f, 0.f);
  rb = *(const float4*)&W[bk * HID + bn];
  sA[0][ak][am] = ra.x;
  sA[0][ak + 1][am] = ra.y;
  *(float4*)&sB[0][bk][bn] = rb;
  __syncthreads();

  float acc[4][8];
#pragma unroll
  for (int r = 0; r < 4; ++r)
#pragma unroll
    for (int c = 0; c < 8; ++c) acc[r][c] = 0.f;

  for (int kb = 0; kb < HID / TK; ++kb) {
    int cur = kb & 1;
    if (kb < HID / TK - 1) {
      int koff = (kb + 1) * TK;
      ra = aok ? *(const float2*)&A[(size_t)agr * HID + koff + ak] : make_float2(0.f, 0.f);
      rb = *(const float4*)&W[(koff + bk) * HID + bn];
    }
#pragma unroll
    for (int k = 0; k < TK; ++k) {
      float4 a = *(float4*)&sA[cur][k][m0];
      float4 b0 = *(float4*)&sB[cur][k][n0];
      float4 b1 = *(float4*)&sB[cur][k][n0 + 4];
      const float av[4] = {a.x, a.y, a.z, a.w};
      const float bv[8] = {b0.x, b0.y, b0.z, b0.w, b1.x, b1.y, b1.z, b1.w};
#pragma unroll
      for (int r = 0; r < 4; ++r)
#pragma unroll
        for (int c = 0; c < 8; ++c) acc[r][c] += av[r] * bv[c];
    }
    if (kb < HID / TK - 1) {
      int nxt = cur ^ 1;
      sA[nxt][ak][am] = ra.x;
      sA[nxt][ak + 1][am] = ra.y;
      *(float4*)&sB[nxt][bk][bn] = rb;
      __syncthreads();
    }
  }

#pragma unroll
  for (int r = 0; r < 4; ++r) {
    int gr = row0 + m0 + r;
    if (gr < nrows) {
      float s = dinv[gr];
      float4 o0 = make_float4(s * acc[r][0], s * acc[r][1], s * acc[r][2], s * acc[r][3]);
      float4 o1 = make_float4(s * acc[r][4], s * acc[r][5], s * acc[r][6], s * acc[r][7]);
      *(float4*)&T[(size_t)gr * HID + n0] = o0;
      *(float4*)&T[(size_t)gr * HID + n0 + 4] = o1;
    }
  }
}

// ---------------- aggregate: out[d] = relu(b + dinv[d]*(T[d] + sum_e T[src_e])) ----------------

__global__ __launch_bounds__(256) void aggregate(const float* __restrict__ T,
                                                 const float* __restrict__ dinv,
                                                 const int* __restrict__ row_ptr,
                                                 const int* __restrict__ col_src,
                                                 const float* __restrict__ bias,
                                                 float* __restrict__ Hout, int n) {
  int node = (blockIdx.x * 256 + threadIdx.x) >> 6;
  if (node >= n) return;
  int lane = threadIdx.x & 63;
  int c = lane * 2;
  float2 t0 = *(const float2*)&T[(size_t)node * HID + c];
  float ax = t0.x;
  float ay = t0.y;
  int j = row_ptr[node], end = row_ptr[node + 1];
  for (; j + 4 <= end; j += 4) {
    int s0 = col_src[j], s1 = col_src[j + 1], s2 = col_src[j + 2], s3 = col_src[j + 3];
    float2 v0 = *(const float2*)&T[(size_t)s0 * HID + c];
    float2 v1 = *(const float2*)&T[(size_t)s1 * HID + c];
    float2 v2 = *(const float2*)&T[(size_t)s2 * HID + c];
    float2 v3 = *(const float2*)&T[(size_t)s3 * HID + c];
    ax += v0.x + v1.x + v2.x + v3.x;
    ay += v0.y + v1.y + v2.y + v3.y;
  }
  for (; j < end; ++j) {
    int s = col_src[j];
    float2 v = *(const float2*)&T[(size_t)s * HID + c];
    ax += v.x;
    ay += v.y;
  }
  float di = dinv[node];
  ax = fmaxf(di * ax + bias[c], 0.f);
  ay = fmaxf(di * ay + bias[c + 1], 0.f);
  *(float2*)&Hout[(size_t)node * HID + c] = make_float2(ax, ay);
}

// ---------------- pooling ----------------

__global__ __launch_bounds__(128) void pool_partial(const float* __restrict__ Hin,
                                                    const int* __restrict__ batch,
                                                    float* __restrict__ pooled, int n) {
  int t = threadIdx.x;
  int s = blockIdx.x * 64;
  if (s >= n) return;
  int e = min(s + 64, n);
  int g = batch[s];
  float acc = 0.f;
  for (int i = s; i < e; ++i) {
    int bi = batch[i];
    if (bi != g) {
      atomicAdd(&pooled[g * HID + t], acc);
      acc = 0.f;
      g = bi;
    }
    acc += Hin[(size_t)i * HID + t];
  }
  atomicAdd(&pooled[g * HID + t], acc);
}

__global__ __launch_bounds__(128) void classify_k(const float* __restrict__ pooled,
                                                  const int* __restrict__ batch,
                                                  const float* __restrict__ Wl,
                                                  const float* __restrict__ bl,
                                                  float* __restrict__ out, int n) {
  int g = blockIdx.x;
  int t = threadIdx.x;
  int lo = 0, hi = n;
  while (lo < hi) { int mid = (lo + hi) >> 1; if (batch[mid] < g) lo = mid + 1; else hi = mid; }
  int s = lo;
  hi = n;
  while (lo < hi) { int mid = (lo + hi) >> 1; if (batch[mid] < g + 1) lo = mid + 1; else hi = mid; }
  float c = fmaxf((float)(lo - s), 1.0f);
  __shared__ float p[HID];
  p[t] = pooled[g * HID + t] / c;
  __syncthreads();
  if (t < CLS) {
    float o = bl[t];
    for (int j = 0; j < HID; ++j) o += p[j] * Wl[j * CLS + t];
    out[g * CLS + t] = o;
  }
}

// ---------------- launch ----------------

extern "C" void kernel_launch(void* const* d_in, const int* in_sizes, int n_in,
                              void* d_out, int out_size, void* d_ws, size_t ws_size,
                              hipStream_t stream) {
  const float* x  = (const float*)d_in[0];
  const float* W1 = (const float*)d_in[1];
  const float* b1 = (const float*)d_in[2];
  const float* W2 = (const float*)d_in[3];
  const float* b2 = (const float*)d_in[4];
  const float* W3 = (const float*)d_in[5];
  const float* b3 = (const float*)d_in[6];
  const float* Wl = (const float*)d_in[7];
  const float* bl = (const float*)d_in[8];
  const int* edge_index = (const int*)d_in[9];
  const int* batch = (const int*)d_in[10];

  const int N = in_sizes[10];
  const int E = in_sizes[9] / 2;
  const int G = out_size / CLS;
  const int* src = edge_index;
  const int* dst = edge_index + E;

  uintptr_t p = (uintptr_t)d_ws;
  auto take = [&](size_t bytes) -> void* {
    void* r = (void*)p;
    p += (bytes + 255) & ~(size_t)255;
    return r;
  };
  int*   degi      = (int*)take((size_t)N * 4);
  int*   fillc     = (int*)take((size_t)N * 4);
  int*   row_ptr   = (int*)take((size_t)(N + 1) * 4);
  int*   blockSums = (int*)take(256 * 4);
  float* dinv      = (float*)take((size_t)N * 4);
  int*   col_src   = (int*)take((size_t)E * 4);
  float* bufT      = (float*)take((size_t)N * HID * 4);
  float* bufH      = (float*)take((size_t)N * HID * 4);
  float* pooled    = (float*)take((size_t)G * HID * 4);

  int nbN = (N + 255) / 256;
  int nbE = (E + 255) / 256;

  zero_init<<<nbN, 256, 0, stream>>>(degi, fillc, pooled, N, G * HID);
  degree_k<<<nbE, 256, 0, stream>>>(dst, degi, E);
  dinv_k<<<nbN, 256, 0, stream>>>(degi, dinv, N);
  scan_chunk<<<nbN, 256, 0, stream>>>(degi, row_ptr, blockSums, N);
  scan_top<<<1, 256, 0, stream>>>(blockSums, nbN);
  scan_add<<<nbN, 256, 0, stream>>>(row_ptr, blockSums, N, E);
  csr_fill<<<nbE, 256, 0, stream>>>(src, dst, row_ptr, fillc, col_src, E);

  int gemmBlocks = (N + TM - 1) / TM;
  int aggBlocks = (N * 64 + 255) / 256;

  gemm_scaled<<<gemmBlocks, 256, 0, stream>>>(x, W1, dinv, bufT, N);
  aggregate<<<aggBlocks, 256, 0, stream>>>(bufT, dinv, row_ptr, col_src, b1, bufH, N);
  gemm_scaled<<<gemmBlocks, 256, 0, stream>>>(bufH, W2, dinv, bufT, N);
  aggregate<<<aggBlocks, 256, 0, stream>>>(bufT, dinv, row_ptr, col_src, b2, bufH, N);
  gemm_scaled<<<gemmBlocks, 256, 0, stream>>>(bufH, W3, dinv, bufT, N);
  aggregate<<<aggBlocks, 256, 0, stream>>>(bufT, dinv, row_ptr, col_src, b3, bufH, N);

  pool_partial<<<(N + 63) / 64, 128, 0, stream>>>(bufH, batch, pooled, N);
  classify_k<<<G, 128, 0, stream>>>(pooled, batch, Wl, bl, (float*)d_out, N);
}

// Round 5
// 411.168 us; speedup vs baseline: 1.3685x; 1.0078x over previous
//
#include <hip/hip_runtime.h>

#define HID 128
#define CLS 10

// ---------------- CSR build ----------------

__global__ __launch_bounds__(256) void zero_init(int* degi, int* fillc,
                                                 float* pooled, int n, int gh) {
  int i = blockIdx.x * 256 + threadIdx.x;
  if (i < n) { degi[i] = 0; fillc[i] = 0; }
  if (i < gh) pooled[i] = 0.f;
}

__global__ __launch_bounds__(256) void degree_k(const int* __restrict__ dst,
                                                int* __restrict__ degi, int E) {
  int e = blockIdx.x * 256 + threadIdx.x;
  if (e < E) atomicAdd(&degi[dst[e]], 1);
}

// scan of degrees + dinv computation fused
__global__ __launch_bounds__(256) void scan_chunk(const int* __restrict__ degi,
                                                  int* __restrict__ row_ptr,
                                                  int* __restrict__ blockSums,
                                                  float* __restrict__ dinv, int n) {
  __shared__ int sd[256];
  int t = threadIdx.x;
  int i = blockIdx.x * 256 + t;
  int v = (i < n) ? degi[i] : 0;
  if (i < n) dinv[i] = rsqrtf((float)v + 1.0f);  // +1 self-loop
  sd[t] = v;
  for (int off = 1; off < 256; off <<= 1) {
    __syncthreads();
    int x = (t >= off) ? sd[t - off] : 0;
    __syncthreads();
    sd[t] += x;
  }
  if (i < n) row_ptr[i] = sd[t] - v;
  if (t == 255) blockSums[blockIdx.x] = sd[255];
}

__global__ __launch_bounds__(256) void scan_top(int* blockSums, int nb) {
  __shared__ int sd[256];
  int t = threadIdx.x;
  int v = (t < nb) ? blockSums[t] : 0;
  sd[t] = v;
  for (int off = 1; off < 256; off <<= 1) {
    __syncthreads();
    int x = (t >= off) ? sd[t - off] : 0;
    __syncthreads();
    sd[t] += x;
  }
  if (t < nb) blockSums[t] = sd[t] - v;
}

__global__ __launch_bounds__(256) void scan_add(int* __restrict__ row_ptr,
                                                const int* __restrict__ blockSums,
                                                int n, int E) {
  int i = blockIdx.x * 256 + threadIdx.x;
  if (i < n) row_ptr[i] += blockSums[blockIdx.x];
  if (i == 0) row_ptr[n] = E;
}

__global__ __launch_bounds__(256) void csr_fill(const int* __restrict__ src,
                                                const int* __restrict__ dst,
                                                const int* __restrict__ row_ptr,
                                                int* __restrict__ fillc,
                                                int* __restrict__ col_src, int E) {
  int e = blockIdx.x * 256 + threadIdx.x;
  if (e >= E) return;
  int s = src[e], d = dst[e];
  int slot = atomicAdd(&fillc[d], 1);
  col_src[row_ptr[d] + slot] = s;
}

// ---------------- fp32 GEMM: T[r,:] = dinv[r] * (A[r,:] @ W) ----------------
// M128 x N128 x K8 double-buffered; thread tile 8x8 -> 64 FMAs per 4 ds_read_b128
// (0.5 B/FLOP: VALU-bound, not LDS-bound). LDS 16.6 KB, ~100 VGPR.

#define TM 128
#define TK 8

__global__ __launch_bounds__(256) void gemm_scaled(const float* __restrict__ A,
                                                   const float* __restrict__ W,
                                                   const float* __restrict__ dinv,
                                                   float* __restrict__ T, int nrows) {
  __shared__ float sA[2][TK][TM + 4];  // transposed [k][m], pad 4 keeps 16B align
  __shared__ float sB[2][TK][HID];
  int tid = threadIdx.x;
  int row0 = blockIdx.x * TM;

  // staging coords: A: 128 rows x 8 k = 1024 floats, float4 along k per thread
  int am = tid >> 1;            // 0..127
  int ak = (tid & 1) * 4;       // 0 or 4
  int bk = tid >> 5;            // 0..7
  int bn = (tid & 31) * 4;      // 0..124
  int agr = row0 + am;
  bool aok = (agr < nrows);

  // compute coords: 16x16 threads, each 8 rows x 8 cols
  int m0 = (tid & 15) * 8;
  int n0 = (tid >> 4) * 8;

  float4 ra, rb;

  ra = aok ? *(const float4*)&A[(size_t)agr * HID + ak] : make_float4(0.f, 0.f, 0.f, 0.f);
  rb = *(const float4*)&W[bk * HID + bn];
  sA[0][ak][am] = ra.x;
  sA[0][ak + 1][am] = ra.y;
  sA[0][ak + 2][am] = ra.z;
  sA[0][ak + 3][am] = ra.w;
  *(float4*)&sB[0][bk][bn] = rb;
  __syncthreads();

  float acc[8][8];
#pragma unroll
  for (int r = 0; r < 8; ++r)
#pragma unroll
    for (int c = 0; c < 8; ++c) acc[r][c] = 0.f;

  for (int kb = 0; kb < HID / TK; ++kb) {
    int cur = kb & 1;
    if (kb < HID / TK - 1) {
      int koff = (kb + 1) * TK;
      ra = aok ? *(const float4*)&A[(size_t)agr * HID + koff + ak] : make_float4(0.f, 0.f, 0.f, 0.f);
      rb = *(const float4*)&W[(koff + bk) * HID + bn];
    }
#pragma unroll
    for (int k = 0; k < TK; ++k) {
      float4 a0 = *(float4*)&sA[cur][k][m0];
      float4 a1 = *(float4*)&sA[cur][k][m0 + 4];
      float4 b0 = *(float4*)&sB[cur][k][n0];
      float4 b1 = *(float4*)&sB[cur][k][n0 + 4];
      const float av[8] = {a0.x, a0.y, a0.z, a0.w, a1.x, a1.y, a1.z, a1.w};
      const float bv[8] = {b0.x, b0.y, b0.z, b0.w, b1.x, b1.y, b1.z, b1.w};
#pragma unroll
      for (int r = 0; r < 8; ++r)
#pragma unroll
        for (int c = 0; c < 8; ++c) acc[r][c] += av[r] * bv[c];
    }
    if (kb < HID / TK - 1) {
      int nxt = cur ^ 1;
      sA[nxt][ak][am] = ra.x;
      sA[nxt][ak + 1][am] = ra.y;
      sA[nxt][ak + 2][am] = ra.z;
      sA[nxt][ak + 3][am] = ra.w;
      *(float4*)&sB[nxt][bk][bn] = rb;
      __syncthreads();
    }
  }

#pragma unroll
  for (int r = 0; r < 8; ++r) {
    int gr = row0 + m0 + r;
    if (gr < nrows) {
      float s = dinv[gr];
      float4 o0 = make_float4(s * acc[r][0], s * acc[r][1], s * acc[r][2], s * acc[r][3]);
      float4 o1 = make_float4(s * acc[r][4], s * acc[r][5], s * acc[r][6], s * acc[r][7]);
      *(float4*)&T[(size_t)gr * HID + n0] = o0;
      *(float4*)&T[(size_t)gr * HID + n0 + 4] = o1;
    }
  }
}

// ---------------- aggregate: out[d] = relu(b + dinv[d]*(T[d] + sum_e T[src_e])) ----------------
// One wave per node; batched index loads + deep unroll for memory-level parallelism.

__global__ __launch_bounds__(256) void aggregate(const float* __restrict__ T,
                                                 const float* __restrict__ dinv,
                                                 const int* __restrict__ row_ptr,
                                                 const int* __restrict__ col_src,
                                                 const float* __restrict__ bias,
                                                 float* __restrict__ Hout, int n) {
  int node = (blockIdx.x * 256 + threadIdx.x) >> 6;
  if (node >= n) return;
  int lane = threadIdx.x & 63;
  int c = lane * 2;
  float2 t0 = *(const float2*)&T[(size_t)node * HID + c];
  float ax = t0.x;
  float ay = t0.y;
  int j = row_ptr[node], end = row_ptr[node + 1];
  for (; j + 8 <= end; j += 8) {
    int idx[8];
#pragma unroll
    for (int u = 0; u < 8; ++u) idx[u] = col_src[j + u];
    float2 v[8];
#pragma unroll
    for (int u = 0; u < 8; ++u) v[u] = *(const float2*)&T[(size_t)idx[u] * HID + c];
#pragma unroll
    for (int u = 0; u < 8; ++u) { ax += v[u].x; ay += v[u].y; }
  }
  if (j + 4 <= end) {
    int idx[4];
#pragma unroll
    for (int u = 0; u < 4; ++u) idx[u] = col_src[j + u];
    float2 v[4];
#pragma unroll
    for (int u = 0; u < 4; ++u) v[u] = *(const float2*)&T[(size_t)idx[u] * HID + c];
#pragma unroll
    for (int u = 0; u < 4; ++u) { ax += v[u].x; ay += v[u].y; }
    j += 4;
  }
  for (; j < end; ++j) {
    int s = col_src[j];
    float2 v = *(const float2*)&T[(size_t)s * HID + c];
    ax += v.x;
    ay += v.y;
  }
  float di = dinv[node];
  ax = fmaxf(di * ax + bias[c], 0.f);
  ay = fmaxf(di * ay + bias[c + 1], 0.f);
  *(float2*)&Hout[(size_t)node * HID + c] = make_float2(ax, ay);
}

// ---------------- pooling ----------------

__global__ __launch_bounds__(128) void pool_partial(const float* __restrict__ Hin,
                                                    const int* __restrict__ batch,
                                                    float* __restrict__ pooled, int n) {
  int t = threadIdx.x;
  int s = blockIdx.x * 64;
  if (s >= n) return;
  int e = min(s + 64, n);
  int g = batch[s];
  float acc = 0.f;
  for (int i = s; i < e; ++i) {
    int bi = batch[i];
    if (bi != g) {
      atomicAdd(&pooled[g * HID + t], acc);
      acc = 0.f;
      g = bi;
    }
    acc += Hin[(size_t)i * HID + t];
  }
  atomicAdd(&pooled[g * HID + t], acc);
}

__global__ __launch_bounds__(128) void classify_k(const float* __restrict__ pooled,
                                                  const int* __restrict__ batch,
                                                  const float* __restrict__ Wl,
                                                  const float* __restrict__ bl,
                                                  float* __restrict__ out, int n) {
  int g = blockIdx.x;
  int t = threadIdx.x;
  int lo = 0, hi = n;
  while (lo < hi) { int mid = (lo + hi) >> 1; if (batch[mid] < g) lo = mid + 1; else hi = mid; }
  int s = lo;
  hi = n;
  while (lo < hi) { int mid = (lo + hi) >> 1; if (batch[mid] < g + 1) lo = mid + 1; else hi = mid; }
  float c = fmaxf((float)(lo - s), 1.0f);
  __shared__ float p[HID];
  p[t] = pooled[g * HID + t] / c;
  __syncthreads();
  if (t < CLS) {
    float o = bl[t];
    for (int j = 0; j < HID; ++j) o += p[j] * Wl[j * CLS + t];
    out[g * CLS + t] = o;
  }
}

// ---------------- launch ----------------

extern "C" void kernel_launch(void* const* d_in, const int* in_sizes, int n_in,
                              void* d_out, int out_size, void* d_ws, size_t ws_size,
                              hipStream_t stream) {
  const float* x  = (const float*)d_in[0];
  const float* W1 = (const float*)d_in[1];
  const float* b1 = (const float*)d_in[2];
  const float* W2 = (const float*)d_in[3];
  const float* b2 = (const float*)d_in[4];
  const float* W3 = (const float*)d_in[5];
  const float* b3 = (const float*)d_in[6];
  const float* Wl = (const float*)d_in[7];
  const float* bl = (const float*)d_in[8];
  const int* edge_index = (const int*)d_in[9];
  const int* batch = (const int*)d_in[10];

  const int N = in_sizes[10];
  const int E = in_sizes[9] / 2;
  const int G = out_size / CLS;
  const int* src = edge_index;
  const int* dst = edge_index + E;

  uintptr_t p = (uintptr_t)d_ws;
  auto take = [&](size_t bytes) -> void* {
    void* r = (void*)p;
    p += (bytes + 255) & ~(size_t)255;
    return r;
  };
  int*   degi      = (int*)take((size_t)N * 4);
  int*   fillc     = (int*)take((size_t)N * 4);
  int*   row_ptr   = (int*)take((size_t)(N + 1) * 4);
  int*   blockSums = (int*)take(256 * 4);
  float* dinv      = (float*)take((size_t)N * 4);
  int*   col_src   = (int*)take((size_t)E * 4);
  float* bufT      = (float*)take((size_t)N * HID * 4);
  float* bufH      = (float*)take((size_t)N * HID * 4);
  float* pooled    = (float*)take((size_t)G * HID * 4);

  int nbN = (N + 255) / 256;
  int nbE = (E + 255) / 256;

  zero_init<<<nbN, 256, 0, stream>>>(degi, fillc, pooled, N, G * HID);
  degree_k<<<nbE, 256, 0, stream>>>(dst, degi, E);
  scan_chunk<<<nbN, 256, 0, stream>>>(degi, row_ptr, blockSums, dinv, N);
  scan_top<<<1, 256, 0, stream>>>(blockSums, nbN);
  scan_add<<<nbN, 256, 0, stream>>>(row_ptr, blockSums, N, E);
  csr_fill<<<nbE, 256, 0, stream>>>(src, dst, row_ptr, fillc, col_src, E);

  int gemmBlocks = (N + TM - 1) / TM;
  int aggBlocks = (N * 64 + 255) / 256;

  gemm_scaled<<<gemmBlocks, 256, 0, stream>>>(x, W1, dinv, bufT, N);
  aggregate<<<aggBlocks, 256, 0, stream>>>(bufT, dinv, row_ptr, col_src, b1, bufH, N);
  gemm_scaled<<<gemmBlocks, 256, 0, stream>>>(bufH, W2, dinv, bufT, N);
  aggregate<<<aggBlocks, 256, 0, stream>>>(bufT, dinv, row_ptr, col_src, b2, bufH, N);
  gemm_scaled<<<gemmBlocks, 256, 0, stream>>>(bufH, W3, dinv, bufT, N);
  aggregate<<<aggBlocks, 256, 0, stream>>>(bufT, dinv, row_ptr, col_src, b3, bufH, N);

  pool_partial<<<(N + 63) / 64, 128, 0, stream>>>(bufH, batch, pooled, N);
  classify_k<<<G, 128, 0, stream>>>(pooled, batch, Wl, bl, (float*)d_out, N);
}

// Round 6
// 369.149 us; speedup vs baseline: 1.5243x; 1.1138x over previous
//
#include <hip/hip_runtime.h>

#define HID 128
#define CLS 10

// float -> bf16 round-to-nearest-even
__device__ __forceinline__ unsigned short f2bf(float f) {
  union { float f; unsigned u; } v; v.f = f;
  unsigned u = v.u;
  return (unsigned short)((u + 0x7FFFu + ((u >> 16) & 1u)) >> 16);
}

// ---------------- CSR build ----------------

__global__ __launch_bounds__(256) void zero_init(int* degi, int* fillc,
                                                 float* pooled, int n, int gh) {
  int i = blockIdx.x * 256 + threadIdx.x;
  if (i < n) { degi[i] = 0; fillc[i] = 0; }
  if (i < gh) pooled[i] = 0.f;
}

__global__ __launch_bounds__(256) void degree_k(const int* __restrict__ dst,
                                                int* __restrict__ degi, int E) {
  int e = blockIdx.x * 256 + threadIdx.x;
  if (e < E) atomicAdd(&degi[dst[e]], 1);
}

// scan of degrees + dinv computation fused
__global__ __launch_bounds__(256) void scan_chunk(const int* __restrict__ degi,
                                                  int* __restrict__ row_ptr,
                                                  int* __restrict__ blockSums,
                                                  float* __restrict__ dinv, int n) {
  __shared__ int sd[256];
  int t = threadIdx.x;
  int i = blockIdx.x * 256 + t;
  int v = (i < n) ? degi[i] : 0;
  if (i < n) dinv[i] = rsqrtf((float)v + 1.0f);  // +1 self-loop
  sd[t] = v;
  for (int off = 1; off < 256; off <<= 1) {
    __syncthreads();
    int x = (t >= off) ? sd[t - off] : 0;
    __syncthreads();
    sd[t] += x;
  }
  if (i < n) row_ptr[i] = sd[t] - v;
  if (t == 255) blockSums[blockIdx.x] = sd[255];
}

__global__ __launch_bounds__(256) void scan_top(int* blockSums, int nb) {
  __shared__ int sd[256];
  int t = threadIdx.x;
  int v = (t < nb) ? blockSums[t] : 0;
  sd[t] = v;
  for (int off = 1; off < 256; off <<= 1) {
    __syncthreads();
    int x = (t >= off) ? sd[t - off] : 0;
    __syncthreads();
    sd[t] += x;
  }
  if (t < nb) blockSums[t] = sd[t] - v;
}

__global__ __launch_bounds__(256) void scan_add(int* __restrict__ row_ptr,
                                                const int* __restrict__ blockSums,
                                                int n, int E) {
  int i = blockIdx.x * 256 + threadIdx.x;
  if (i < n) row_ptr[i] += blockSums[blockIdx.x];
  if (i == 0) row_ptr[n] = E;
}

__global__ __launch_bounds__(256) void csr_fill(const int* __restrict__ src,
                                                const int* __restrict__ dst,
                                                const int* __restrict__ row_ptr,
                                                int* __restrict__ fillc,
                                                int* __restrict__ col_src, int E) {
  int e = blockIdx.x * 256 + threadIdx.x;
  if (e >= E) return;
  int s = src[e], d = dst[e];
  int slot = atomicAdd(&fillc[d], 1);
  col_src[row_ptr[d] + slot] = s;
}

// ---------------- fp32 GEMM: Tb[r,:] = bf16( dinv[r] * (A[r,:] @ W) ) ----------------
// M128 x N128 x K8 double-buffered; thread tile 8x8. Output is bf16-packed only
// (halves epilogue write traffic and, more importantly, halves gather bytes in aggregate).

#define TM 128
#define TK 8

__global__ __launch_bounds__(256) void gemm_scaled(const float* __restrict__ A,
                                                   const float* __restrict__ W,
                                                   const float* __restrict__ dinv,
                                                   unsigned* __restrict__ Tb2,  // bf16x2, N x 64
                                                   int nrows) {
  __shared__ float sA[2][TK][TM + 4];
  __shared__ float sB[2][TK][HID];
  int tid = threadIdx.x;
  int row0 = blockIdx.x * TM;

  int am = tid >> 1;
  int ak = (tid & 1) * 4;
  int bk = tid >> 5;
  int bn = (tid & 31) * 4;
  int agr = row0 + am;
  bool aok = (agr < nrows);

  int m0 = (tid & 15) * 8;
  int n0 = (tid >> 4) * 8;

  float4 ra, rb;

  ra = aok ? *(const float4*)&A[(size_t)agr * HID + ak] : make_float4(0.f, 0.f, 0.f, 0.f);
  rb = *(const float4*)&W[bk * HID + bn];
  sA[0][ak][am] = ra.x;
  sA[0][ak + 1][am] = ra.y;
  sA[0][ak + 2][am] = ra.z;
  sA[0][ak + 3][am] = ra.w;
  *(float4*)&sB[0][bk][bn] = rb;
  __syncthreads();

  float acc[8][8];
#pragma unroll
  for (int r = 0; r < 8; ++r)
#pragma unroll
    for (int c = 0; c < 8; ++c) acc[r][c] = 0.f;

  for (int kb = 0; kb < HID / TK; ++kb) {
    int cur = kb & 1;
    if (kb < HID / TK - 1) {
      int koff = (kb + 1) * TK;
      ra = aok ? *(const float4*)&A[(size_t)agr * HID + koff + ak] : make_float4(0.f, 0.f, 0.f, 0.f);
      rb = *(const float4*)&W[(koff + bk) * HID + bn];
    }
#pragma unroll
    for (int k = 0; k < TK; ++k) {
      float4 a0 = *(float4*)&sA[cur][k][m0];
      float4 a1 = *(float4*)&sA[cur][k][m0 + 4];
      float4 b0 = *(float4*)&sB[cur][k][n0];
      float4 b1 = *(float4*)&sB[cur][k][n0 + 4];
      const float av[8] = {a0.x, a0.y, a0.z, a0.w, a1.x, a1.y, a1.z, a1.w};
      const float bv[8] = {b0.x, b0.y, b0.z, b0.w, b1.x, b1.y, b1.z, b1.w};
#pragma unroll
      for (int r = 0; r < 8; ++r)
#pragma unroll
        for (int c = 0; c < 8; ++c) acc[r][c] += av[r] * bv[c];
    }
    if (kb < HID / TK - 1) {
      int nxt = cur ^ 1;
      sA[nxt][ak][am] = ra.x;
      sA[nxt][ak + 1][am] = ra.y;
      sA[nxt][ak + 2][am] = ra.z;
      sA[nxt][ak + 3][am] = ra.w;
      *(float4*)&sB[nxt][bk][bn] = rb;
      __syncthreads();
    }
  }

#pragma unroll
  for (int r = 0; r < 8; ++r) {
    int gr = row0 + m0 + r;
    if (gr < nrows) {
      float s = dinv[gr];
      uint4 o;
      o.x = (unsigned)f2bf(s * acc[r][0]) | ((unsigned)f2bf(s * acc[r][1]) << 16);
      o.y = (unsigned)f2bf(s * acc[r][2]) | ((unsigned)f2bf(s * acc[r][3]) << 16);
      o.z = (unsigned)f2bf(s * acc[r][4]) | ((unsigned)f2bf(s * acc[r][5]) << 16);
      o.w = (unsigned)f2bf(s * acc[r][6]) | ((unsigned)f2bf(s * acc[r][7]) << 16);
      *(uint4*)&Tb2[(size_t)gr * 64 + (n0 >> 1)] = o;
    }
  }
}

// ---------------- aggregate: out[d] = relu(b + dinv[d]*(Tb[d] + sum_e Tb[src_e])) ----------------
// One wave per node; each lane owns cols 2*lane,2*lane+1 = one packed bf16x2 (4 B) per row.

__global__ __launch_bounds__(256) void aggregate(const unsigned* __restrict__ Tb2,
                                                 const float* __restrict__ dinv,
                                                 const int* __restrict__ row_ptr,
                                                 const int* __restrict__ col_src,
                                                 const float* __restrict__ bias,
                                                 float* __restrict__ Hout, int n) {
  int node = (blockIdx.x * 256 + threadIdx.x) >> 6;
  if (node >= n) return;
  int lane = threadIdx.x & 63;
  int c = lane * 2;
  unsigned v0 = Tb2[(size_t)node * 64 + lane];
  float ax = __uint_as_float(v0 << 16);
  float ay = __uint_as_float(v0 & 0xFFFF0000u);
  int j = row_ptr[node], end = row_ptr[node + 1];
  for (; j + 8 <= end; j += 8) {
    int idx[8];
#pragma unroll
    for (int u = 0; u < 8; ++u) idx[u] = col_src[j + u];
    unsigned v[8];
#pragma unroll
    for (int u = 0; u < 8; ++u) v[u] = Tb2[(size_t)idx[u] * 64 + lane];
#pragma unroll
    for (int u = 0; u < 8; ++u) {
      ax += __uint_as_float(v[u] << 16);
      ay += __uint_as_float(v[u] & 0xFFFF0000u);
    }
  }
  if (j + 4 <= end) {
    int idx[4];
#pragma unroll
    for (int u = 0; u < 4; ++u) idx[u] = col_src[j + u];
    unsigned v[4];
#pragma unroll
    for (int u = 0; u < 4; ++u) v[u] = Tb2[(size_t)idx[u] * 64 + lane];
#pragma unroll
    for (int u = 0; u < 4; ++u) {
      ax += __uint_as_float(v[u] << 16);
      ay += __uint_as_float(v[u] & 0xFFFF0000u);
    }
    j += 4;
  }
  for (; j < end; ++j) {
    unsigned v = Tb2[(size_t)col_src[j] * 64 + lane];
    ax += __uint_as_float(v << 16);
    ay += __uint_as_float(v & 0xFFFF0000u);
  }
  float di = dinv[node];
  ax = fmaxf(di * ax + bias[c], 0.f);
  ay = fmaxf(di * ay + bias[c + 1], 0.f);
  *(float2*)&Hout[(size_t)node * HID + c] = make_float2(ax, ay);
}

// ---------------- pooling ----------------

__global__ __launch_bounds__(128) void pool_partial(const float* __restrict__ Hin,
                                                    const int* __restrict__ batch,
                                                    float* __restrict__ pooled, int n) {
  int t = threadIdx.x;
  int s = blockIdx.x * 64;
  if (s >= n) return;
  int e = min(s + 64, n);
  int g = batch[s];
  float acc = 0.f;
  for (int i = s; i < e; ++i) {
    int bi = batch[i];
    if (bi != g) {
      atomicAdd(&pooled[g * HID + t], acc);
      acc = 0.f;
      g = bi;
    }
    acc += Hin[(size_t)i * HID + t];
  }
  atomicAdd(&pooled[g * HID + t], acc);
}

__global__ __launch_bounds__(128) void classify_k(const float* __restrict__ pooled,
                                                  const int* __restrict__ batch,
                                                  const float* __restrict__ Wl,
                                                  const float* __restrict__ bl,
                                                  float* __restrict__ out, int n) {
  int g = blockIdx.x;
  int t = threadIdx.x;
  int lo = 0, hi = n;
  while (lo < hi) { int mid = (lo + hi) >> 1; if (batch[mid] < g) lo = mid + 1; else hi = mid; }
  int s = lo;
  hi = n;
  while (lo < hi) { int mid = (lo + hi) >> 1; if (batch[mid] < g + 1) lo = mid + 1; else hi = mid; }
  float c = fmaxf((float)(lo - s), 1.0f);
  __shared__ float p[HID];
  p[t] = pooled[g * HID + t] / c;
  __syncthreads();
  if (t < CLS) {
    float o = bl[t];
    for (int j = 0; j < HID; ++j) o += p[j] * Wl[j * CLS + t];
    out[g * CLS + t] = o;
  }
}

// ---------------- launch ----------------

extern "C" void kernel_launch(void* const* d_in, const int* in_sizes, int n_in,
                              void* d_out, int out_size, void* d_ws, size_t ws_size,
                              hipStream_t stream) {
  const float* x  = (const float*)d_in[0];
  const float* W1 = (const float*)d_in[1];
  const float* b1 = (const float*)d_in[2];
  const float* W2 = (const float*)d_in[3];
  const float* b2 = (const float*)d_in[4];
  const float* W3 = (const float*)d_in[5];
  const float* b3 = (const float*)d_in[6];
  const float* Wl = (const float*)d_in[7];
  const float* bl = (const float*)d_in[8];
  const int* edge_index = (const int*)d_in[9];
  const int* batch = (const int*)d_in[10];

  const int N = in_sizes[10];
  const int E = in_sizes[9] / 2;
  const int G = out_size / CLS;
  const int* src = edge_index;
  const int* dst = edge_index + E;

  uintptr_t p = (uintptr_t)d_ws;
  auto take = [&](size_t bytes) -> void* {
    void* r = (void*)p;
    p += (bytes + 255) & ~(size_t)255;
    return r;
  };
  int*      degi      = (int*)take((size_t)N * 4);
  int*      fillc     = (int*)take((size_t)N * 4);
  int*      row_ptr   = (int*)take((size_t)(N + 1) * 4);
  int*      blockSums = (int*)take(256 * 4);
  float*    dinv      = (float*)take((size_t)N * 4);
  int*      col_src   = (int*)take((size_t)E * 4);
  unsigned* bufTb     = (unsigned*)take((size_t)N * 64 * 4);  // bf16x2 packed
  float*    bufH      = (float*)take((size_t)N * HID * 4);
  float*    pooled    = (float*)take((size_t)G * HID * 4);

  int nbN = (N + 255) / 256;
  int nbE = (E + 255) / 256;

  zero_init<<<nbN, 256, 0, stream>>>(degi, fillc, pooled, N, G * HID);
  degree_k<<<nbE, 256, 0, stream>>>(dst, degi, E);
  scan_chunk<<<nbN, 256, 0, stream>>>(degi, row_ptr, blockSums, dinv, N);
  scan_top<<<1, 256, 0, stream>>>(blockSums, nbN);
  scan_add<<<nbN, 256, 0, stream>>>(row_ptr, blockSums, N, E);
  csr_fill<<<nbE, 256, 0, stream>>>(src, dst, row_ptr, fillc, col_src, E);

  int gemmBlocks = (N + TM - 1) / TM;
  int aggBlocks = (N * 64 + 255) / 256;

  gemm_scaled<<<gemmBlocks, 256, 0, stream>>>(x, W1, dinv, bufTb, N);
  aggregate<<<aggBlocks, 256, 0, stream>>>(bufTb, dinv, row_ptr, col_src, b1, bufH, N);
  gemm_scaled<<<gemmBlocks, 256, 0, stream>>>(bufH, W2, dinv, bufTb, N);
  aggregate<<<aggBlocks, 256, 0, stream>>>(bufTb, dinv, row_ptr, col_src, b2, bufH, N);
  gemm_scaled<<<gemmBlocks, 256, 0, stream>>>(bufH, W3, dinv, bufTb, N);
  aggregate<<<aggBlocks, 256, 0, stream>>>(bufTb, dinv, row_ptr, col_src, b3, bufH, N);

  pool_partial<<<(N + 63) / 64, 128, 0, stream>>>(bufH, batch, pooled, N);
  classify_k<<<G, 128, 0, stream>>>(pooled, batch, Wl, bl, (float*)d_out, N);
}

// Round 7
// 330.331 us; speedup vs baseline: 1.7034x; 1.1175x over previous
//
#include <hip/hip_runtime.h>

#define HID 128
#define CLS 10

typedef short short8 __attribute__((ext_vector_type(8)));
typedef float f32x4 __attribute__((ext_vector_type(4)));

// float -> bf16 round-to-nearest-even
__device__ __forceinline__ unsigned short f2bf(float f) {
  union { float f; unsigned u; } v; v.f = f;
  unsigned u = v.u;
  return (unsigned short)((u + 0x7FFFu + ((u >> 16) & 1u)) >> 16);
}
__device__ __forceinline__ float bf_lo(unsigned p) { return __uint_as_float(p << 16); }
__device__ __forceinline__ float bf_hi(unsigned p) { return __uint_as_float(p & 0xFFFF0000u); }

// ---------------- CSR build ----------------

__global__ __launch_bounds__(256) void zero_init(int* degi, int* fillc,
                                                 float* pooled, int n, int gh) {
  int i = blockIdx.x * 256 + threadIdx.x;
  if (i < n) { degi[i] = 0; fillc[i] = 0; }
  if (i < gh) pooled[i] = 0.f;
}

__global__ __launch_bounds__(256) void degree_k(const int* __restrict__ dst,
                                                int* __restrict__ degi, int E) {
  int e = blockIdx.x * 256 + threadIdx.x;
  if (e < E) atomicAdd(&degi[dst[e]], 1);
}

__global__ __launch_bounds__(256) void scan_chunk(const int* __restrict__ degi,
                                                  int* __restrict__ row_ptr,
                                                  int* __restrict__ blockSums,
                                                  float* __restrict__ dinv, int n) {
  __shared__ int sd[256];
  int t = threadIdx.x;
  int i = blockIdx.x * 256 + t;
  int v = (i < n) ? degi[i] : 0;
  if (i < n) dinv[i] = rsqrtf((float)v + 1.0f);  // +1 self-loop
  sd[t] = v;
  for (int off = 1; off < 256; off <<= 1) {
    __syncthreads();
    int x = (t >= off) ? sd[t - off] : 0;
    __syncthreads();
    sd[t] += x;
  }
  if (i < n) row_ptr[i] = sd[t] - v;
  if (t == 255) blockSums[blockIdx.x] = sd[255];
}

__global__ __launch_bounds__(256) void scan_top(int* blockSums, int nb) {
  __shared__ int sd[256];
  int t = threadIdx.x;
  int v = (t < nb) ? blockSums[t] : 0;
  sd[t] = v;
  for (int off = 1; off < 256; off <<= 1) {
    __syncthreads();
    int x = (t >= off) ? sd[t - off] : 0;
    __syncthreads();
    sd[t] += x;
  }
  if (t < nb) blockSums[t] = sd[t] - v;
}

__global__ __launch_bounds__(256) void scan_add(int* __restrict__ row_ptr,
                                                const int* __restrict__ blockSums,
                                                int n, int E) {
  int i = blockIdx.x * 256 + threadIdx.x;
  if (i < n) row_ptr[i] += blockSums[blockIdx.x];
  if (i == 0) row_ptr[n] = E;
}

__global__ __launch_bounds__(256) void csr_fill(const int* __restrict__ src,
                                                const int* __restrict__ dst,
                                                const int* __restrict__ row_ptr,
                                                int* __restrict__ fillc,
                                                int* __restrict__ col_src, int E) {
  int e = blockIdx.x * 256 + threadIdx.x;
  if (e >= E) return;
  int s = src[e], d = dst[e];
  int slot = atomicAdd(&fillc[d], 1);
  col_src[row_ptr[d] + slot] = s;
}

// ---------------- converts ----------------

// x fp32 [N][128] -> packed bf16x2 [N][64]
__global__ __launch_bounds__(256) void cvt_x(const float* __restrict__ x,
                                             unsigned* __restrict__ Xb, int n64) {
  int i = blockIdx.x * 256 + threadIdx.x;
  if (i < n64) {
    float2 v = *(const float2*)&x[(size_t)i * 2];
    Xb[i] = (unsigned)f2bf(v.x) | ((unsigned)f2bf(v.y) << 16);
  }
}

// W fp32 [k][n] -> Wt bf16 [n][k] for the MFMA B-operand (k-contiguous per column)
__global__ __launch_bounds__(256) void wt_build(const float* __restrict__ W1,
                                                const float* __restrict__ W2,
                                                const float* __restrict__ W3,
                                                unsigned short* __restrict__ Wt) {
  const float* W = (blockIdx.x == 0) ? W1 : (blockIdx.x == 1) ? W2 : W3;
  unsigned short* o = Wt + (size_t)blockIdx.x * HID * HID;
  for (int idx = threadIdx.x; idx < HID * HID; idx += 256) {
    int k = idx >> 7, nn = idx & 127;
    o[nn * HID + k] = f2bf(W[idx]);
  }
}

// ---------------- MFMA bf16 GEMM: Tb[r,:] = bf16( dinv[r] * (A[r,:] @ W) ) ----------------
// Block = 4 waves x 32 rows = 128 rows. W staged in LDS (transposed, padded);
// A fragments loaded direct global->VGPR (bf16 native). K=128 fully unrolled,
// 16x16x32 bf16 MFMA: wave = 2 row-tiles x 8 col-tiles x 4 k-steps = 64 MFMAs.

#define WTP 136  // 128 + 8 pad (272 B row stride, 16B-aligned, min-phase b128 reads)

__global__ __launch_bounds__(256) void gemm_mfma(const unsigned* __restrict__ Ab,  // bf16x2 [n][64]
                                                 const unsigned short* __restrict__ Wt,  // bf16 [n][k]
                                                 const float* __restrict__ dinv,
                                                 unsigned short* __restrict__ Tb,  // bf16 [n][128]
                                                 int nrows) {
  __shared__ unsigned short sW[HID][WTP];
  int tid = threadIdx.x;
  int wave = tid >> 6, lane = tid & 63;
  int m_lo = lane & 15, quad = lane >> 4;
  int row0 = blockIdx.x * 128;
  int rbase = row0 + wave * 32;

  // A fragments: 2 row-tiles x 4 k-blocks, 16 B each (8 bf16), issued before barrier
  uint4 araw[2][4];
#pragma unroll
  for (int tr = 0; tr < 2; ++tr) {
    int grow = rbase + tr * 16 + m_lo;
    int gr = (grow < nrows) ? grow : (nrows - 1);  // clamp: stores are guarded later
    const uint4* Arow = (const uint4*)&Ab[(size_t)gr * 64];
#pragma unroll
    for (int kb = 0; kb < 4; ++kb) araw[tr][kb] = Arow[kb * 4 + quad];
  }

  // stage Wt (32 KB) as 2048 uint4, 8 per thread
  const uint4* Wt4 = (const uint4*)Wt;
#pragma unroll
  for (int i = 0; i < 8; ++i) {
    int idx = i * 256 + tid;
    int nn = idx >> 4;
    int kk = (idx & 15) * 8;
    *(uint4*)&sW[nn][kk] = Wt4[idx];
  }
  __syncthreads();

  f32x4 acc[2][8];
#pragma unroll
  for (int tr = 0; tr < 2; ++tr)
#pragma unroll
    for (int tc = 0; tc < 8; ++tc) acc[tr][tc] = (f32x4)(0.f);

#pragma unroll
  for (int kb = 0; kb < 4; ++kb) {
    short8 b[8];
#pragma unroll
    for (int tc = 0; tc < 8; ++tc) {
      union { uint4 u; short8 s; } cv;
      cv.u = *(const uint4*)&sW[tc * 16 + m_lo][kb * 32 + quad * 8];
      b[tc] = cv.s;
    }
#pragma unroll
    for (int tr = 0; tr < 2; ++tr) {
      union { uint4 u; short8 s; } av;
      av.u = araw[tr][kb];
#pragma unroll
      for (int tc = 0; tc < 8; ++tc)
        acc[tr][tc] = __builtin_amdgcn_mfma_f32_16x16x32_bf16(av.s, b[tc], acc[tr][tc], 0, 0, 0);
    }
  }

  // epilogue: D[row=(quad*4+r)][col=lane&15] per tile; scale by dinv, store bf16
#pragma unroll
  for (int tr = 0; tr < 2; ++tr) {
#pragma unroll
    for (int r = 0; r < 4; ++r) {
      int grow = rbase + tr * 16 + quad * 4 + r;
      if (grow < nrows) {
        float s = dinv[grow];
        unsigned short* orow = &Tb[(size_t)grow * HID];
#pragma unroll
        for (int tc = 0; tc < 8; ++tc)
          orow[tc * 16 + m_lo] = f2bf(s * acc[tr][tc][r]);
      }
    }
  }
}

// ---------------- aggregate: Hb[d] = bf16( relu(b + dinv[d]*(Tb[d] + sum_e Tb[src_e])) ) ----------------

__global__ __launch_bounds__(256) void aggregate(const unsigned* __restrict__ Tb2,
                                                 const float* __restrict__ dinv,
                                                 const int* __restrict__ row_ptr,
                                                 const int* __restrict__ col_src,
                                                 const float* __restrict__ bias,
                                                 unsigned* __restrict__ Hb, int n) {
  int node = (blockIdx.x * 256 + threadIdx.x) >> 6;
  if (node >= n) return;
  int lane = threadIdx.x & 63;
  int c = lane * 2;
  unsigned v0 = Tb2[(size_t)node * 64 + lane];
  float ax = bf_lo(v0);
  float ay = bf_hi(v0);
  int j = row_ptr[node], end = row_ptr[node + 1];
  for (; j + 8 <= end; j += 8) {
    int idx[8];
#pragma unroll
    for (int u = 0; u < 8; ++u) idx[u] = col_src[j + u];
    unsigned v[8];
#pragma unroll
    for (int u = 0; u < 8; ++u) v[u] = Tb2[(size_t)idx[u] * 64 + lane];
#pragma unroll
    for (int u = 0; u < 8; ++u) { ax += bf_lo(v[u]); ay += bf_hi(v[u]); }
  }
  if (j + 4 <= end) {
    int idx[4];
#pragma unroll
    for (int u = 0; u < 4; ++u) idx[u] = col_src[j + u];
    unsigned v[4];
#pragma unroll
    for (int u = 0; u < 4; ++u) v[u] = Tb2[(size_t)idx[u] * 64 + lane];
#pragma unroll
    for (int u = 0; u < 4; ++u) { ax += bf_lo(v[u]); ay += bf_hi(v[u]); }
    j += 4;
  }
  for (; j < end; ++j) {
    unsigned v = Tb2[(size_t)col_src[j] * 64 + lane];
    ax += bf_lo(v);
    ay += bf_hi(v);
  }
  float di = dinv[node];
  ax = fmaxf(di * ax + bias[c], 0.f);
  ay = fmaxf(di * ay + bias[c + 1], 0.f);
  Hb[(size_t)node * 64 + lane] = (unsigned)f2bf(ax) | ((unsigned)f2bf(ay) << 16);
}

// ---------------- pooling (reads packed bf16 H) ----------------

__global__ __launch_bounds__(64) void pool_partial(const unsigned* __restrict__ Hb,
                                                   const int* __restrict__ batch,
                                                   float* __restrict__ pooled, int n) {
  int t = threadIdx.x;  // col pair
  int s = blockIdx.x * 64;
  if (s >= n) return;
  int e = min(s + 64, n);
  int g = batch[s];
  float ax = 0.f, ay = 0.f;
  for (int i = s; i < e; ++i) {
    int bi = batch[i];
    if (bi != g) {
      atomicAdd(&pooled[g * HID + 2 * t], ax);
      atomicAdd(&pooled[g * HID + 2 * t + 1], ay);
      ax = ay = 0.f;
      g = bi;
    }
    unsigned v = Hb[(size_t)i * 64 + t];
    ax += bf_lo(v);
    ay += bf_hi(v);
  }
  atomicAdd(&pooled[g * HID + 2 * t], ax);
  atomicAdd(&pooled[g * HID + 2 * t + 1], ay);
}

__global__ __launch_bounds__(128) void classify_k(const float* __restrict__ pooled,
                                                  const int* __restrict__ batch,
                                                  const float* __restrict__ Wl,
                                                  const float* __restrict__ bl,
                                                  float* __restrict__ out, int n) {
  int g = blockIdx.x;
  int t = threadIdx.x;
  int lo = 0, hi = n;
  while (lo < hi) { int mid = (lo + hi) >> 1; if (batch[mid] < g) lo = mid + 1; else hi = mid; }
  int s = lo;
  hi = n;
  while (lo < hi) { int mid = (lo + hi) >> 1; if (batch[mid] < g + 1) lo = mid + 1; else hi = mid; }
  float c = fmaxf((float)(lo - s), 1.0f);
  __shared__ float p[HID];
  p[t] = pooled[g * HID + t] / c;
  __syncthreads();
  if (t < CLS) {
    float o = bl[t];
    for (int j = 0; j < HID; ++j) o += p[j] * Wl[j * CLS + t];
    out[g * CLS + t] = o;
  }
}

// ---------------- launch ----------------

extern "C" void kernel_launch(void* const* d_in, const int* in_sizes, int n_in,
                              void* d_out, int out_size, void* d_ws, size_t ws_size,
                              hipStream_t stream) {
  const float* x  = (const float*)d_in[0];
  const float* W1 = (const float*)d_in[1];
  const float* b1 = (const float*)d_in[2];
  const float* W2 = (const float*)d_in[3];
  const float* b2 = (const float*)d_in[4];
  const float* W3 = (const float*)d_in[5];
  const float* b3 = (const float*)d_in[6];
  const float* Wl = (const float*)d_in[7];
  const float* bl = (const float*)d_in[8];
  const int* edge_index = (const int*)d_in[9];
  const int* batch = (const int*)d_in[10];

  const int N = in_sizes[10];
  const int E = in_sizes[9] / 2;
  const int G = out_size / CLS;
  const int* src = edge_index;
  const int* dst = edge_index + E;

  uintptr_t p = (uintptr_t)d_ws;
  auto take = [&](size_t bytes) -> void* {
    void* r = (void*)p;
    p += (bytes + 255) & ~(size_t)255;
    return r;
  };
  int*      degi      = (int*)take((size_t)N * 4);
  int*      fillc     = (int*)take((size_t)N * 4);
  int*      row_ptr   = (int*)take((size_t)(N + 1) * 4);
  int*      blockSums = (int*)take(256 * 4);
  float*    dinv      = (float*)take((size_t)N * 4);
  int*      col_src   = (int*)take((size_t)E * 4);
  unsigned* bufXb     = (unsigned*)take((size_t)N * 64 * 4);   // bf16x2 packed x
  unsigned short* WtA = (unsigned short*)take((size_t)3 * HID * HID * 2);
  unsigned short* bufTb = (unsigned short*)take((size_t)N * HID * 2);
  unsigned* bufHb     = (unsigned*)take((size_t)N * 64 * 4);   // bf16x2 packed H
  float*    pooled    = (float*)take((size_t)G * HID * 4);

  int nbN = (N + 255) / 256;
  int nbE = (E + 255) / 256;

  zero_init<<<nbN, 256, 0, stream>>>(degi, fillc, pooled, N, G * HID);
  cvt_x<<<(N * 64 + 255) / 256, 256, 0, stream>>>(x, bufXb, N * 64);
  wt_build<<<3, 256, 0, stream>>>(W1, W2, W3, WtA);
  degree_k<<<nbE, 256, 0, stream>>>(dst, degi, E);
  scan_chunk<<<nbN, 256, 0, stream>>>(degi, row_ptr, blockSums, dinv, N);
  scan_top<<<1, 256, 0, stream>>>(blockSums, nbN);
  scan_add<<<nbN, 256, 0, stream>>>(row_ptr, blockSums, N, E);
  csr_fill<<<nbE, 256, 0, stream>>>(src, dst, row_ptr, fillc, col_src, E);

  int gemmBlocks = (N + 127) / 128;
  int aggBlocks = (N * 64 + 255) / 256;

  gemm_mfma<<<gemmBlocks, 256, 0, stream>>>(bufXb, WtA, dinv, bufTb, N);
  aggregate<<<aggBlocks, 256, 0, stream>>>((unsigned*)bufTb, dinv, row_ptr, col_src, b1, bufHb, N);
  gemm_mfma<<<gemmBlocks, 256, 0, stream>>>(bufHb, WtA + (size_t)HID * HID, dinv, bufTb, N);
  aggregate<<<aggBlocks, 256, 0, stream>>>((unsigned*)bufTb, dinv, row_ptr, col_src, b2, bufHb, N);
  gemm_mfma<<<gemmBlocks, 256, 0, stream>>>(bufHb, WtA + (size_t)2 * HID * HID, dinv, bufTb, N);
  aggregate<<<aggBlocks, 256, 0, stream>>>((unsigned*)bufTb, dinv, row_ptr, col_src, b3, bufHb, N);

  pool_partial<<<(N + 63) / 64, 64, 0, stream>>>(bufHb, batch, pooled, N);
  classify_k<<<G, 128, 0, stream>>>(pooled, batch, Wl, bl, (float*)d_out, N);
}

// Round 8
// 300.738 us; speedup vs baseline: 1.8710x; 1.0984x over previous
//
#include <hip/hip_runtime.h>

#define HID 128
#define CLS 10

typedef short short8 __attribute__((ext_vector_type(8)));
typedef float f32x4 __attribute__((ext_vector_type(4)));

// float -> bf16 round-to-nearest-even
__device__ __forceinline__ unsigned short f2bf(float f) {
  union { float f; unsigned u; } v; v.f = f;
  unsigned u = v.u;
  return (unsigned short)((u + 0x7FFFu + ((u >> 16) & 1u)) >> 16);
}
__device__ __forceinline__ float bf_lo(unsigned p) { return __uint_as_float(p << 16); }
__device__ __forceinline__ float bf_hi(unsigned p) { return __uint_as_float(p & 0xFFFF0000u); }

// ---------------- CSR build ----------------

__global__ __launch_bounds__(256) void zero_init(int* degi, int n) {
  int i = blockIdx.x * 256 + threadIdx.x;
  if (i < n) degi[i] = 0;
}

__global__ __launch_bounds__(256) void degree_k(const int* __restrict__ dst,
                                                int* __restrict__ degi, int E) {
  int e = blockIdx.x * 256 + threadIdx.x;
  if (e < E) atomicAdd(&degi[dst[e]], 1);
}

// scan of degrees + dinv + zeroing of fillc/pooled (both consumed later)
__global__ __launch_bounds__(256) void scan_chunk(const int* __restrict__ degi,
                                                  int* __restrict__ row_ptr,
                                                  int* __restrict__ blockSums,
                                                  float* __restrict__ dinv,
                                                  int* __restrict__ fillc,
                                                  float* __restrict__ pooled,
                                                  int n, int gh) {
  __shared__ int sd[256];
  int t = threadIdx.x;
  int i = blockIdx.x * 256 + t;
  int v = (i < n) ? degi[i] : 0;
  if (i < n) { dinv[i] = rsqrtf((float)v + 1.0f); fillc[i] = 0; }  // +1 self-loop
  if (i < gh) pooled[i] = 0.f;
  sd[t] = v;
  for (int off = 1; off < 256; off <<= 1) {
    __syncthreads();
    int x = (t >= off) ? sd[t - off] : 0;
    __syncthreads();
    sd[t] += x;
  }
  if (i < n) row_ptr[i] = sd[t] - v;
  if (t == 255) blockSums[blockIdx.x] = sd[255];
}

__global__ __launch_bounds__(256) void scan_top(int* blockSums, int nb) {
  __shared__ int sd[256];
  int t = threadIdx.x;
  int v = (t < nb) ? blockSums[t] : 0;
  sd[t] = v;
  for (int off = 1; off < 256; off <<= 1) {
    __syncthreads();
    int x = (t >= off) ? sd[t - off] : 0;
    __syncthreads();
    sd[t] += x;
  }
  if (t < nb) blockSums[t] = sd[t] - v;
}

__global__ __launch_bounds__(256) void scan_add(int* __restrict__ row_ptr,
                                                const int* __restrict__ blockSums,
                                                int n, int E) {
  int i = blockIdx.x * 256 + threadIdx.x;
  if (i < n) row_ptr[i] += blockSums[blockIdx.x];
  if (i == 0) row_ptr[n] = E;
}

__global__ __launch_bounds__(256) void csr_fill(const int* __restrict__ src,
                                                const int* __restrict__ dst,
                                                const int* __restrict__ row_ptr,
                                                int* __restrict__ fillc,
                                                int* __restrict__ col_src, int E) {
  int e = blockIdx.x * 256 + threadIdx.x;
  if (e >= E) return;
  int s = src[e], d = dst[e];
  int slot = atomicAdd(&fillc[d], 1);
  col_src[row_ptr[d] + slot] = s;
}

// W fp32 [k][n] -> Wt bf16 [n][k] (MFMA B-operand layout). 16 blocks per matrix.
__global__ __launch_bounds__(256) void wt_build(const float* __restrict__ W1,
                                                const float* __restrict__ W2,
                                                const float* __restrict__ W3,
                                                unsigned short* __restrict__ Wt) {
  int mat = blockIdx.x >> 4;         // 0..2
  int part = blockIdx.x & 15;        // 0..15
  const float* W = (mat == 0) ? W1 : (mat == 1) ? W2 : W3;
  unsigned short* o = Wt + (size_t)mat * HID * HID;
  int base = part * (HID * HID / 16);
  for (int r = 0; r < HID * HID / 16; r += 256) {
    int idx = base + r + threadIdx.x;
    int k = idx >> 7, nn = idx & 127;
    o[nn * HID + k] = f2bf(W[idx]);
  }
}

// ---------------- MFMA bf16 GEMM: Tb[r,:] = bf16( dinv[r] * (A[r,:] @ W) ) ----------------
// Block = 4 waves x 32 rows = 128 rows. W staged in LDS (transposed, padded);
// A fragments loaded direct global->VGPR. a_fp32 selects fp32-input path
// (layer 1 reads x directly, converting in-register - no cvt pass).

#define WTP 136  // 128 + 8 pad

__global__ __launch_bounds__(256) void gemm_mfma(const void* __restrict__ Aptr,
                                                 int a_fp32,
                                                 const unsigned short* __restrict__ Wt,  // bf16 [n][k]
                                                 const float* __restrict__ dinv,
                                                 unsigned short* __restrict__ Tb,  // bf16 [n][128]
                                                 int nrows) {
  __shared__ unsigned short sW[HID][WTP];
  int tid = threadIdx.x;
  int wave = tid >> 6, lane = tid & 63;
  int m_lo = lane & 15, quad = lane >> 4;
  int row0 = blockIdx.x * 128;
  int rbase = row0 + wave * 32;

  // A fragments: 2 row-tiles x 4 k-blocks, 8 bf16 each
  uint4 araw[2][4];
#pragma unroll
  for (int tr = 0; tr < 2; ++tr) {
    int grow = rbase + tr * 16 + m_lo;
    int gr = (grow < nrows) ? grow : (nrows - 1);  // clamp: stores guarded later
    if (a_fp32) {
      const float* Arow = (const float*)Aptr + (size_t)gr * HID;
#pragma unroll
      for (int kb = 0; kb < 4; ++kb) {
        float4 f0 = *(const float4*)&Arow[kb * 32 + quad * 8];
        float4 f1 = *(const float4*)&Arow[kb * 32 + quad * 8 + 4];
        uint4 u;
        u.x = (unsigned)f2bf(f0.x) | ((unsigned)f2bf(f0.y) << 16);
        u.y = (unsigned)f2bf(f0.z) | ((unsigned)f2bf(f0.w) << 16);
        u.z = (unsigned)f2bf(f1.x) | ((unsigned)f2bf(f1.y) << 16);
        u.w = (unsigned)f2bf(f1.z) | ((unsigned)f2bf(f1.w) << 16);
        araw[tr][kb] = u;
      }
    } else {
      const uint4* Arow = (const uint4*)((const unsigned*)Aptr + (size_t)gr * 64);
#pragma unroll
      for (int kb = 0; kb < 4; ++kb) araw[tr][kb] = Arow[kb * 4 + quad];
    }
  }

  // stage Wt (32 KB) as 2048 uint4, 8 per thread
  const uint4* Wt4 = (const uint4*)Wt;
#pragma unroll
  for (int i = 0; i < 8; ++i) {
    int idx = i * 256 + tid;
    int nn = idx >> 4;
    int kk = (idx & 15) * 8;
    *(uint4*)&sW[nn][kk] = Wt4[idx];
  }
  __syncthreads();

  f32x4 acc[2][8];
#pragma unroll
  for (int tr = 0; tr < 2; ++tr)
#pragma unroll
    for (int tc = 0; tc < 8; ++tc) acc[tr][tc] = (f32x4)(0.f);

#pragma unroll
  for (int kb = 0; kb < 4; ++kb) {
    short8 b[8];
#pragma unroll
    for (int tc = 0; tc < 8; ++tc) {
      union { uint4 u; short8 s; } cv;
      cv.u = *(const uint4*)&sW[tc * 16 + m_lo][kb * 32 + quad * 8];
      b[tc] = cv.s;
    }
#pragma unroll
    for (int tr = 0; tr < 2; ++tr) {
      union { uint4 u; short8 s; } av;
      av.u = araw[tr][kb];
#pragma unroll
      for (int tc = 0; tc < 8; ++tc)
        acc[tr][tc] = __builtin_amdgcn_mfma_f32_16x16x32_bf16(av.s, b[tc], acc[tr][tc], 0, 0, 0);
    }
  }

  // epilogue: D[row=(quad*4+r)][col=lane&15]; scale by dinv, store bf16
#pragma unroll
  for (int tr = 0; tr < 2; ++tr) {
#pragma unroll
    for (int r = 0; r < 4; ++r) {
      int grow = rbase + tr * 16 + quad * 4 + r;
      if (grow < nrows) {
        float s = dinv[grow];
        unsigned short* orow = &Tb[(size_t)grow * HID];
#pragma unroll
        for (int tc = 0; tc < 8; ++tc)
          orow[tc * 16 + m_lo] = f2bf(s * acc[tr][tc][r]);
      }
    }
  }
}

// ---------------- aggregate: Hb[d] = bf16( relu(b + dinv[d]*(Tb[d] + sum_e Tb[src_e])) ) ----------------

__global__ __launch_bounds__(256) void aggregate(const unsigned* __restrict__ Tb2,
                                                 const float* __restrict__ dinv,
                                                 const int* __restrict__ row_ptr,
                                                 const int* __restrict__ col_src,
                                                 const float* __restrict__ bias,
                                                 unsigned* __restrict__ Hb, int n) {
  int node = (blockIdx.x * 256 + threadIdx.x) >> 6;
  if (node >= n) return;
  int lane = threadIdx.x & 63;
  int c = lane * 2;
  unsigned v0 = Tb2[(size_t)node * 64 + lane];
  float ax = bf_lo(v0);
  float ay = bf_hi(v0);
  int j = row_ptr[node], end = row_ptr[node + 1];
  for (; j + 8 <= end; j += 8) {
    int idx[8];
#pragma unroll
    for (int u = 0; u < 8; ++u) idx[u] = col_src[j + u];
    unsigned v[8];
#pragma unroll
    for (int u = 0; u < 8; ++u) v[u] = Tb2[(size_t)idx[u] * 64 + lane];
#pragma unroll
    for (int u = 0; u < 8; ++u) { ax += bf_lo(v[u]); ay += bf_hi(v[u]); }
  }
  if (j + 4 <= end) {
    int idx[4];
#pragma unroll
    for (int u = 0; u < 4; ++u) idx[u] = col_src[j + u];
    unsigned v[4];
#pragma unroll
    for (int u = 0; u < 4; ++u) v[u] = Tb2[(size_t)idx[u] * 64 + lane];
#pragma unroll
    for (int u = 0; u < 4; ++u) { ax += bf_lo(v[u]); ay += bf_hi(v[u]); }
    j += 4;
  }
  for (; j < end; ++j) {
    unsigned v = Tb2[(size_t)col_src[j] * 64 + lane];
    ax += bf_lo(v);
    ay += bf_hi(v);
  }
  float di = dinv[node];
  ax = fmaxf(di * ax + bias[c], 0.f);
  ay = fmaxf(di * ay + bias[c + 1], 0.f);
  Hb[(size_t)node * 64 + lane] = (unsigned)f2bf(ax) | ((unsigned)f2bf(ay) << 16);
}

// ---------------- pooling (reads packed bf16 H); 16 nodes per block ----------------

__global__ __launch_bounds__(64) void pool_partial(const unsigned* __restrict__ Hb,
                                                   const int* __restrict__ batch,
                                                   float* __restrict__ pooled, int n) {
  int t = threadIdx.x;  // col pair
  int s = blockIdx.x * 16;
  if (s >= n) return;
  int e = min(s + 16, n);
  int g = batch[s];
  float ax = 0.f, ay = 0.f;
  for (int i = s; i < e; ++i) {
    int bi = batch[i];
    if (bi != g) {
      atomicAdd(&pooled[g * HID + 2 * t], ax);
      atomicAdd(&pooled[g * HID + 2 * t + 1], ay);
      ax = ay = 0.f;
      g = bi;
    }
    unsigned v = Hb[(size_t)i * 64 + t];
    ax += bf_lo(v);
    ay += bf_hi(v);
  }
  atomicAdd(&pooled[g * HID + 2 * t], ax);
  atomicAdd(&pooled[g * HID + 2 * t + 1], ay);
}

__global__ __launch_bounds__(128) void classify_k(const float* __restrict__ pooled,
                                                  const int* __restrict__ batch,
                                                  const float* __restrict__ Wl,
                                                  const float* __restrict__ bl,
                                                  float* __restrict__ out, int n) {
  int g = blockIdx.x;
  int t = threadIdx.x;
  int lo = 0, hi = n;
  while (lo < hi) { int mid = (lo + hi) >> 1; if (batch[mid] < g) lo = mid + 1; else hi = mid; }
  int s = lo;
  hi = n;
  while (lo < hi) { int mid = (lo + hi) >> 1; if (batch[mid] < g + 1) lo = mid + 1; else hi = mid; }
  float c = fmaxf((float)(lo - s), 1.0f);
  __shared__ float p[HID];
  p[t] = pooled[g * HID + t] / c;
  __syncthreads();
  if (t < CLS) {
    float o = bl[t];
    for (int j = 0; j < HID; ++j) o += p[j] * Wl[j * CLS + t];
    out[g * CLS + t] = o;
  }
}

// ---------------- launch ----------------

extern "C" void kernel_launch(void* const* d_in, const int* in_sizes, int n_in,
                              void* d_out, int out_size, void* d_ws, size_t ws_size,
                              hipStream_t stream) {
  const float* x  = (const float*)d_in[0];
  const float* W1 = (const float*)d_in[1];
  const float* b1 = (const float*)d_in[2];
  const float* W2 = (const float*)d_in[3];
  const float* b2 = (const float*)d_in[4];
  const float* W3 = (const float*)d_in[5];
  const float* b3 = (const float*)d_in[6];
  const float* Wl = (const float*)d_in[7];
  const float* bl = (const float*)d_in[8];
  const int* edge_index = (const int*)d_in[9];
  const int* batch = (const int*)d_in[10];

  const int N = in_sizes[10];
  const int E = in_sizes[9] / 2;
  const int G = out_size / CLS;
  const int* src = edge_index;
  const int* dst = edge_index + E;

  uintptr_t p = (uintptr_t)d_ws;
  auto take = [&](size_t bytes) -> void* {
    void* r = (void*)p;
    p += (bytes + 255) & ~(size_t)255;
    return r;
  };
  int*      degi      = (int*)take((size_t)N * 4);
  int*      fillc     = (int*)take((size_t)N * 4);
  int*      row_ptr   = (int*)take((size_t)(N + 1) * 4);
  int*      blockSums = (int*)take(256 * 4);
  float*    dinv      = (float*)take((size_t)N * 4);
  int*      col_src   = (int*)take((size_t)E * 4);
  unsigned short* WtA = (unsigned short*)take((size_t)3 * HID * HID * 2);
  unsigned short* bufTb = (unsigned short*)take((size_t)N * HID * 2);
  unsigned* bufHb     = (unsigned*)take((size_t)N * 64 * 4);   // bf16x2 packed H
  float*    pooled    = (float*)take((size_t)G * HID * 4);

  int nbN = (N + 255) / 256;
  int nbE = (E + 255) / 256;

  zero_init<<<nbN, 256, 0, stream>>>(degi, N);
  wt_build<<<48, 256, 0, stream>>>(W1, W2, W3, WtA);
  degree_k<<<nbE, 256, 0, stream>>>(dst, degi, E);
  scan_chunk<<<nbN, 256, 0, stream>>>(degi, row_ptr, blockSums, dinv, fillc, pooled, N, G * HID);
  scan_top<<<1, 256, 0, stream>>>(blockSums, nbN);
  scan_add<<<nbN, 256, 0, stream>>>(row_ptr, blockSums, N, E);
  csr_fill<<<nbE, 256, 0, stream>>>(src, dst, row_ptr, fillc, col_src, E);

  int gemmBlocks = (N + 127) / 128;
  int aggBlocks = (N * 64 + 255) / 256;

  gemm_mfma<<<gemmBlocks, 256, 0, stream>>>(x, 1, WtA, dinv, bufTb, N);
  aggregate<<<aggBlocks, 256, 0, stream>>>((unsigned*)bufTb, dinv, row_ptr, col_src, b1, bufHb, N);
  gemm_mfma<<<gemmBlocks, 256, 0, stream>>>(bufHb, 0, WtA + (size_t)HID * HID, dinv, bufTb, N);
  aggregate<<<aggBlocks, 256, 0, stream>>>((unsigned*)bufTb, dinv, row_ptr, col_src, b2, bufHb, N);
  gemm_mfma<<<gemmBlocks, 256, 0, stream>>>(bufHb, 0, WtA + (size_t)2 * HID * HID, dinv, bufTb, N);
  aggregate<<<aggBlocks, 256, 0, stream>>>((unsigned*)bufTb, dinv, row_ptr, col_src, b3, bufHb, N);

  pool_partial<<<(N + 15) / 16, 64, 0, stream>>>(bufHb, batch, pooled, N);
  classify_k<<<G, 128, 0, stream>>>(pooled, batch, Wl, bl, (float*)d_out, N);
}